// Round 1
// 689.344 us; speedup vs baseline: 1.2129x; 1.2129x over previous
//
#include <hip/hip_runtime.h>
#include <hip/hip_bf16.h>

// ---------------------------------------------------------------------------
// Performer (FAVOR+) attention, MI355X gfx950.  f32 I/O, bf16 MFMA internals.
// R8: S1 and S5 moved to a 256x256/BK=64/512-thr double-buffered pipeline
// GEMM (gemm256): global_load_lds staging with COUNTED vmcnt(8) across raw
// s_barriers (no __syncthreads vmcnt(0) drain), XOR-16B LDS swizzle
// (conflict-free ds_read_b128), XCD-aware block swizzle, setprio on MFMA
// cluster.  Small phase-A/B GEMMs keep the proven 128^2 m97 structure.
//   prep:  wqkvt(3072x1024)=bf16([Wq|Wk|Wv]^T); wot=bf16(Wo^T); projb padded
//   S1:    [Qb|Kb|Vb](16384x1024 bf16 each) = xb . wqkvt^T   (gemm256 EPI7)
//   phase A, per n-chunk c (1024 rows x 4):
//     S2k: kptc[bh](288x1024) = relu(projb . K_c^T)+eps, rows>=266->0 (EPI2)
//     vtc[bh](65x1024)        = [V_c^T ; ones]
//     S3:  kvxf[bh](65x288)  += vtc . kptc^T  f32 accumulate (EPI6)
//   finalize: kvxb = bf16(kvxf)
//   phase B, per chunk c:
//     S2q: qpc[bh](1024x288) = relu(Q_c . projb^T)+eps, cols>=266->0 (EPI1)
//     S4:  outm rows c       = (qpc . kvxb^T)/denom, merged heads (EPI4)
//   S5:    out(f32) = outm . wot^T + bo (gemm256 EPI5)
// Aliases: xb=chunk (dead before phase A); outm=Kb (dead after phase A);
// qpc=kptc=chunk.  ws total 162.5 MB (proven fit).
// ---------------------------------------------------------------------------

typedef __bf16 bf16x8 __attribute__((ext_vector_type(8)));
typedef float  f32x4  __attribute__((ext_vector_type(4)));

#define EPS_F 1e-3f

__device__ __forceinline__ void gld16(const void* g, void* l) {
  __builtin_amdgcn_global_load_lds(
      (const __attribute__((address_space(1))) void*)g,
      (__attribute__((address_space(3))) void*)l, 16, 0, 0);
}

// ---------------------------------------------------------------------------
// gemm256: 256x256 tile, BK=64, 8 waves (2M x 4N), per-wave 128x64 output.
// LDS 128 KiB = 2 buffers x (A 32K | B 32K).  Staging: linear LDS dest,
// pre-swizzled global source (16B granule g' = (t&7) ^ (row&7)); reads XOR
// the same pattern -> conflict-free ds_read_b128 (rule #21 both-sides).
// Schedule per K-tile (2 raw barriers, counted vmcnt):
//   reads(24 b128) -> MFMA(64) -> bar -> STAGE(t+2 into cur) -> vmcnt(8)
//   -> bar -> swap.   Tail iters use vmcnt(0) (also drains before endpgm).
// Requires M%256==0, N%256==0, K%64==0, grid%8==0.
// EPI=7: bf16 store split into Q/K/V slabs.  EPI=5: f32 + bias.
// ---------------------------------------------------------------------------
template <int EPI>
__global__ void __launch_bounds__(512, 2)
gemm256(const __hip_bfloat16* __restrict__ A, long lda,
        const __hip_bfloat16* __restrict__ Bt, long ldb,
        void* __restrict__ Cp, long ldc,
        int Mtiles, int Ntiles, int K, const float* __restrict__ bias) {
  __shared__ __align__(16) char sm[131072];

  const int tid  = threadIdx.x;
  const int lane = tid & 63;
  const int wave = tid >> 6;   // 0..7
  const int wm   = wave >> 2;  // 0..1
  const int wn   = wave & 3;   // 0..3
  const int quad = lane >> 4;
  const int l15  = lane & 15;

  // XCD-aware bijective swizzle (nwg % 8 == 0 in all uses)
  const int nwg = Mtiles * Ntiles;
  const int cpx = nwg >> 3;
  const int bid = blockIdx.x;
  const int wid = (bid & 7) * cpx + (bid >> 3);
  const int nt  = wid / Mtiles;   // N-tile outer: XCD chunk shares B panel
  const int mt  = wid - nt * Mtiles;
  const long m0 = (long)mt * 256;
  const long n0 = (long)nt * 256;

  // staging: thread t, instr i covers tile row i*64+(t>>3); source granule
  // pre-swizzled so linear LDS dest holds the swizzled layout.
  const int srow = tid >> 3;                 // 0..63
  const int sg   = (tid & 7) ^ (srow & 7);   // 16B granule in row
  const __hip_bfloat16* aS = A  + (m0 + srow) * lda + sg * 8;
  const __hip_bfloat16* bS = Bt + (n0 + srow) * ldb + sg * 8;
  char* smc = (char*)sm;
  const int ldsOff = tid * 16;

  // fragment read bases; col-byte XOR'd with (row&7)<<4 (row&7 == l15&7)
  const int aRowB = (wm * 128 + l15) * 128;
  const int bRowB = 32768 + (wn * 64 + l15) * 128;
  const int sw    = (l15 & 7) << 4;
  const int cx0   = (quad * 16) ^ sw;        // ks=0
  const int cx1   = (64 + quad * 16) ^ sw;   // ks=1

  f32x4 acc[8][4] = {};

#define STAGE256(pp, kk)                                                     \
  {                                                                          \
    char* ab = smc + (pp) * 65536;                                           \
    _Pragma("unroll") for (int i = 0; i < 4; ++i) {                          \
      gld16(aS + (long)i * 64 * lda + (kk), ab + i * 8192 + ldsOff);         \
      gld16(bS + (long)i * 64 * ldb + (kk), ab + 32768 + i * 8192 + ldsOff); \
    }                                                                        \
  }

  const int NT = K >> 6;
  STAGE256(0, 0)
  STAGE256(1, 64)
  asm volatile("s_waitcnt vmcnt(8)" ::: "memory");  // tile 0 resident (mine)
  __builtin_amdgcn_s_barrier();                     // ...and everyone's
  asm volatile("" ::: "memory");

  int p = 0;
  for (int t = 0; t < NT; ++t) {
    const char* base = smc + p * 65536;
    bf16x8 bfr[4][2];
#pragma unroll
    for (int jt = 0; jt < 4; ++jt) {
      bfr[jt][0] = *(const bf16x8*)(base + bRowB + jt * 2048 + cx0);
      bfr[jt][1] = *(const bf16x8*)(base + bRowB + jt * 2048 + cx1);
    }
    __builtin_amdgcn_s_setprio(1);
#pragma unroll
    for (int ih = 0; ih < 2; ++ih) {
      bf16x8 af[4][2];
#pragma unroll
      for (int it = 0; it < 4; ++it) {
        af[it][0] = *(const bf16x8*)(base + aRowB + (ih * 4 + it) * 2048 + cx0);
        af[it][1] = *(const bf16x8*)(base + aRowB + (ih * 4 + it) * 2048 + cx1);
      }
#pragma unroll
      for (int it = 0; it < 4; ++it)
#pragma unroll
        for (int jt = 0; jt < 4; ++jt) {
          acc[ih * 4 + it][jt] = __builtin_amdgcn_mfma_f32_16x16x32_bf16(
              af[it][0], bfr[jt][0], acc[ih * 4 + it][jt], 0, 0, 0);
          acc[ih * 4 + it][jt] = __builtin_amdgcn_mfma_f32_16x16x32_bf16(
              af[it][1], bfr[jt][1], acc[ih * 4 + it][jt], 0, 0, 0);
        }
    }
    __builtin_amdgcn_s_setprio(0);
    __builtin_amdgcn_s_barrier();  // all waves done reading buf p
    asm volatile("" ::: "memory");
    if (t + 2 < NT) {
      STAGE256(p, (long)(t + 2) * 64)
      // counted: 16 outstanding, wait until only t+2's 8 remain
      asm volatile("s_waitcnt vmcnt(8)" ::: "memory");
    } else {
      asm volatile("s_waitcnt vmcnt(0)" ::: "memory");  // tail drain
    }
    __builtin_amdgcn_s_barrier();  // tile t+1 resident for all waves
    asm volatile("" ::: "memory");
    p ^= 1;
  }
#undef STAGE256

  // epilogue: row = wm*128 + it*16 + quad*4 + i, col = wn*64 + jt*16 + l15
  if constexpr (EPI == 7) {
    __hip_bfloat16* Cb = (__hip_bfloat16*)Cp;
    const long slab  = (n0 >> 10) * 16777216;   // Q/K/V slab (tile inside one)
    const long ncol0 = (n0 & 1023) + wn * 64 + l15;
#pragma unroll
    for (int it = 0; it < 8; ++it) {
#pragma unroll
      for (int i = 0; i < 4; ++i) {
        const long gm = m0 + wm * 128 + it * 16 + quad * 4 + i;
        __hip_bfloat16* rowp = Cb + slab + gm * 1024 + ncol0;
#pragma unroll
        for (int jt = 0; jt < 4; ++jt)
          rowp[jt * 16] = (__hip_bfloat16)acc[it][jt][i];
      }
    }
  } else if constexpr (EPI == 5) {
    float* Cf = (float*)Cp;
    float bv[4];
#pragma unroll
    for (int jt = 0; jt < 4; ++jt)
      bv[jt] = bias[n0 + wn * 64 + jt * 16 + l15];
#pragma unroll
    for (int it = 0; it < 8; ++it) {
#pragma unroll
      for (int i = 0; i < 4; ++i) {
        const long gm = m0 + wm * 128 + it * 16 + quad * 4 + i;
        float* rowp = Cf + gm * ldc + n0 + wn * 64 + l15;
#pragma unroll
        for (int jt = 0; jt < 4; ++jt)
          rowp[jt * 16] = acc[it][jt][i] + bv[jt];
      }
    }
  }
}

// ---------------------------------------------------------------------------
// 128^2 m97-structure GEMM for the small phase-A/B ops (unchanged from R7).
// EPI: 1 relu+eps col>=266->0 | 2 relu+eps row>=266->0 | 4 /denom(col 64),
// bf16 merged-head | 6 f32 +=
// ---------------------------------------------------------------------------
template <int EPI>
__global__ void __launch_bounds__(256, 2)
gemm_nt(const __hip_bfloat16* __restrict__ A, long lda, long sAb, long sAh,
        const __hip_bfloat16* __restrict__ Bt, long ldb, long sBb, long sBh,
        void* __restrict__ Cp, long ldc, long sCb, long sCh,
        int M, int N, int K, const float* __restrict__ bias) {
  __shared__ __align__(16) __hip_bfloat16 As[4096];  // 128x32 bf16, chunk-major
  __shared__ __align__(16) __hip_bfloat16 Bs[4096];
  __shared__ float Dsh[128];  // EPI4 denominator broadcast

  const int tid  = threadIdx.x;
  const int lane = tid & 63;
  const int wave = tid >> 6;
  const int quad = lane >> 4;
  const int l15  = lane & 15;
  const int wm   = wave >> 1;
  const int wn   = wave & 1;
  const int m0   = blockIdx.x * 128;
  const int n0   = blockIdx.y * 128;
  const int bz   = blockIdx.z;
  const int bb   = bz >> 4, hh = bz & 15;

  A  += (long)bb * sAb + (long)hh * sAh;
  Bt += (long)bb * sBb + (long)hh * sBh;

  const int  mr   = tid & 127;
  const int  cc   = tid >> 7;  // 0/1
  const long aoff = (long)min(m0 + mr, M - 1) * lda + cc * 8;  // row-clamped
  const long boff = (long)min(n0 + mr, N - 1) * ldb + cc * 8;
  char* AsB = (char*)As;
  char* BsB = (char*)Bs;
  const int ldst = tid * 16;

  f32x4 acc[4][4] = {};

  for (int k0 = 0; k0 < K; k0 += 32) {
    gld16(A + aoff + k0,       AsB + ldst);
    gld16(A + aoff + k0 + 16,  AsB + ldst + 4096);
    gld16(Bt + boff + k0,      BsB + ldst);
    gld16(Bt + boff + k0 + 16, BsB + ldst + 4096);
    __syncthreads();  // drains vmcnt -> LDS valid

    const char* ap = (const char*)As + quad * 2048 + (wm * 64 + l15) * 16;
    const char* bp = (const char*)Bs + quad * 2048 + (wn * 64 + l15) * 16;
    bf16x8 af[4], bfr[4];
#pragma unroll
    for (int it = 0; it < 4; ++it) af[it] = *(const bf16x8*)(ap + it * 256);
#pragma unroll
    for (int jt = 0; jt < 4; ++jt) bfr[jt] = *(const bf16x8*)(bp + jt * 256);
#pragma unroll
    for (int it = 0; it < 4; ++it)
#pragma unroll
      for (int jt = 0; jt < 4; ++jt)
        acc[it][jt] = __builtin_amdgcn_mfma_f32_16x16x32_bf16(
            af[it], bfr[jt], acc[it][jt], 0, 0, 0);
    __syncthreads();
  }

  const long cbase = (long)bb * sCb + (long)hh * sCh;

  if constexpr (EPI == 4) {
    // denominator = col 64 -> wave wn==1, tile jt=0, lanes l15==0
    if (wn == 1 && l15 == 0) {
#pragma unroll
      for (int it = 0; it < 4; ++it)
#pragma unroll
        for (int i = 0; i < 4; ++i)
          Dsh[wm * 64 + it * 16 + quad * 4 + i] = acc[it][0][i];
    }
    __syncthreads();
    if (wn == 0) {  // cols 0..63 = HC dims
      __hip_bfloat16* C = (__hip_bfloat16*)Cp;
#pragma unroll
      for (int it = 0; it < 4; ++it) {
#pragma unroll
        for (int i = 0; i < 4; ++i) {
          const int   row = wm * 64 + it * 16 + quad * 4 + i;
          const float den = Dsh[row];
          const float dinv = (den > 1e-30f) ? (1.0f / den) : 0.0f;
          const long  gm   = m0 + row;
#pragma unroll
          for (int jt = 0; jt < 4; ++jt) {
            const int col = jt * 16 + l15;
            C[cbase + gm * ldc + col] =
                (__hip_bfloat16)(acc[it][jt][i] * dinv);
          }
        }
      }
    }
  } else {
#pragma unroll
    for (int it = 0; it < 4; ++it) {
#pragma unroll
      for (int jt = 0; jt < 4; ++jt) {
#pragma unroll
        for (int i = 0; i < 4; ++i) {
          const int row = wm * 64 + it * 16 + quad * 4 + i;
          const int col = wn * 64 + jt * 16 + l15;
          const int gm = m0 + row, gn = n0 + col;
          if (gm < M && gn < N) {
            float v = acc[it][jt][i];
            if constexpr (EPI == 1) v = (gn < 266) ? (fmaxf(v, 0.f) + EPS_F) : 0.f;
            if constexpr (EPI == 2) v = (gm < 266) ? (fmaxf(v, 0.f) + EPS_F) : 0.f;
            if constexpr (EPI == 6) {
              ((float*)Cp)[cbase + (long)gm * ldc + gn] += v;
            } else {
              ((__hip_bfloat16*)Cp)[cbase + (long)gm * ldc + gn] =
                  (__hip_bfloat16)v;
            }
          }
        }
      }
    }
  }
}

// xb = bf16(x), 8 elements/thread
__global__ void cvt_x(const float* __restrict__ x,
                      __hip_bfloat16* __restrict__ xb) {
  const long i = ((long)blockIdx.x * 256 + threadIdx.x) * 8;
  const float4 f0 = *(const float4*)(x + i);
  const float4 f1 = *(const float4*)(x + i + 4);
  union { __hip_bfloat16 h[8]; uint4 u; } r;
  r.h[0] = (__hip_bfloat16)f0.x; r.h[1] = (__hip_bfloat16)f0.y;
  r.h[2] = (__hip_bfloat16)f0.z; r.h[3] = (__hip_bfloat16)f0.w;
  r.h[4] = (__hip_bfloat16)f1.x; r.h[5] = (__hip_bfloat16)f1.y;
  r.h[6] = (__hip_bfloat16)f1.z; r.h[7] = (__hip_bfloat16)f1.w;
  *(uint4*)(xb + i) = r.u;
}

// all 4 weight transposes in one launch: z in 0..3 picks src/dst.
// dst[n*1024 + k] = bf16(src[k*1024 + n])  (1024x1024, f32 -> bf16)
__global__ void transpose_w4(const float* __restrict__ s0,
                             const float* __restrict__ s1,
                             const float* __restrict__ s2,
                             const float* __restrict__ s3,
                             __hip_bfloat16* __restrict__ dq,
                             __hip_bfloat16* __restrict__ dо_unused,
                             __hip_bfloat16* __restrict__ dwo) {
  __shared__ float t[32][33];
  const int z = blockIdx.z;
  const float* src = (z == 0) ? s0 : (z == 1) ? s1 : (z == 2) ? s2 : s3;
  __hip_bfloat16* dst = (z < 3) ? (dq + (long)z * 1048576) : dwo;
  const int k0 = blockIdx.x * 32, n0 = blockIdx.y * 32;
  const int tx = threadIdx.x & 31, ty = threadIdx.x >> 5;
#pragma unroll
  for (int i = 0; i < 4; ++i)
    t[ty + i * 8][tx] = src[(long)(k0 + ty + i * 8) * 1024 + n0 + tx];
  __syncthreads();
#pragma unroll
  for (int i = 0; i < 4; ++i)
    dst[(long)(n0 + ty + i * 8) * 1024 + k0 + tx] =
        (__hip_bfloat16)t[tx][ty + i * 8];
}

// projb (288x64 bf16): rows<266 = bf16(proj), rows 266..287 exact zero.
__global__ void prep_proj(const float* __restrict__ proj,
                          __hip_bfloat16* __restrict__ projb) {
  const int i = blockIdx.x * 256 + threadIdx.x;
  if (i < 288 * 64) {
    const int r = i >> 6;
    __hip_bfloat16 v = (__hip_bfloat16)0.f;
    if (r < 266) v = (__hip_bfloat16)proj[i];
    projb[i] = v;
  }
}

__global__ void zero_f32(float* __restrict__ p, int n) {
  const int i = blockIdx.x * 256 + threadIdx.x;
  if (i < n) p[i] = 0.f;
}

__global__ void finalize_kvx(const float* __restrict__ kvxf,
                             __hip_bfloat16* __restrict__ kvxb, int n) {
  const int i = blockIdx.x * 256 + threadIdx.x;
  if (i < n) kvxb[i] = (__hip_bfloat16)kvxf[i];
}

// vtc[bh](65x1024) = [V_chunk^T ; ones] from Vb rows c*1024..+1024
__global__ void build_vtc(const __hip_bfloat16* __restrict__ Vb,
                          __hip_bfloat16* __restrict__ vtc, int c) {
  __shared__ __hip_bfloat16 t[64 * 65];
  const int bh = blockIdx.y, n0 = blockIdx.x * 64;
  const int b = bh >> 4, h = bh & 15;
  const int tid = threadIdx.x;
  const __hip_bfloat16* src =
      Vb + ((long)b * 4096 + (long)c * 1024 + n0) * 1024 + h * 64;
  {
    const int d = tid & 63, nr = tid >> 6;
#pragma unroll
    for (int i = 0; i < 16; ++i) {
      const int n = nr * 16 + i;
      t[d * 65 + n] = src[(long)n * 1024 + d];
    }
  }
  __syncthreads();
  __hip_bfloat16* dstb = vtc + (long)bh * 65 * 1024 + n0;
  {
    const int n = tid & 63, dr = tid >> 6;
#pragma unroll
    for (int i = 0; i < 16; ++i) {
      const int dd = dr * 16 + i;
      dstb[(long)dd * 1024 + n] = t[dd * 65 + n];
    }
  }
  if (tid < 64) dstb[(long)64 * 1024 + tid] = (__hip_bfloat16)1.0f;
}

// ---------------------------------------------------------------------------
extern "C" void kernel_launch(void* const* d_in, const int* in_sizes, int n_in,
                              void* d_out, int out_size, void* d_ws,
                              size_t ws_size, hipStream_t stream) {
  const float* x    = (const float*)d_in[0];
  const float* Wq   = (const float*)d_in[1];
  const float* Wk   = (const float*)d_in[2];
  const float* Wv   = (const float*)d_in[3];
  const float* Wo   = (const float*)d_in[4];
  const float* bo   = (const float*)d_in[5];
  const float* proj = (const float*)d_in[6];
  float* out = (float*)d_out;
  char* ws = (char*)d_ws;

  // ws layout (bytes); total 162,545,664 (~155 MiB) — proven fit
  constexpr long o_wqkvt = 0;            // 3072x1024x2 = 6,291,456
  constexpr long o_wot   = 6291456;      // 2,097,152
  constexpr long o_projb = 8388608;      // 36,864
  constexpr long o_Qb    = 8425472;      // 33,554,432
  constexpr long o_Kb    = 41979904;     // 33,554,432 (contiguous; alias outm)
  constexpr long o_Vb    = 75534336;     // 33,554,432 (contiguous)
  constexpr long o_chunk = 109088768;    // 37,748,736 (kptc/qpc; alias xb)
  constexpr long o_vtc   = 146837504;    // 8,519,680
  constexpr long o_kvxf  = 155357184;    // 4,792,320
  constexpr long o_kvxb  = 160149504;    // 2,396,160

  __hip_bfloat16* wqkvt = (__hip_bfloat16*)(ws + o_wqkvt);
  __hip_bfloat16* wot   = (__hip_bfloat16*)(ws + o_wot);
  __hip_bfloat16* projb = (__hip_bfloat16*)(ws + o_projb);
  __hip_bfloat16* Qb    = (__hip_bfloat16*)(ws + o_Qb);
  __hip_bfloat16* Kb    = (__hip_bfloat16*)(ws + o_Kb);
  __hip_bfloat16* Vb    = (__hip_bfloat16*)(ws + o_Vb);
  __hip_bfloat16* chunk = (__hip_bfloat16*)(ws + o_chunk);
  __hip_bfloat16* vtc   = (__hip_bfloat16*)(ws + o_vtc);
  float*          kvxf  = (float*)(ws + o_kvxf);
  __hip_bfloat16* kvxb  = (__hip_bfloat16*)(ws + o_kvxb);
  __hip_bfloat16* xb    = chunk;  // alias: dead before phase A overwrites
  __hip_bfloat16* outm  = Kb;     // alias: Kb dead after phase A
  (void)Vb;

  // prep
  cvt_x<<<8192, 256, 0, stream>>>(x, xb);
  transpose_w4<<<dim3(32, 32, 4), 256, 0, stream>>>(Wq, Wk, Wv, Wo, wqkvt,
                                                    nullptr, wot);
  prep_proj<<<72, 256, 0, stream>>>(proj, projb);
  zero_f32<<<(1198080 + 255) / 256, 256, 0, stream>>>(kvxf, 1198080);

  // S1 fused: [Qb|Kb|Vb] = xb . wqkvt^T   (256^2 pipeline GEMM, EPI7)
  // Mtiles=64 (M=16384), Ntiles=12 (N=3072), grid 768 (%8==0)
  gemm256<7><<<768, 512, 0, stream>>>(xb, 1024, wqkvt, 1024, Qb, 0, 64, 12,
                                      1024, nullptr);

  const long sA_bh  = (long)4096 * 1024;  // Qb/Kb/Vb per-b stride
  const long s_kptc = (long)288 * 1024;
  const long s_vtc  = (long)65 * 1024;
  const long s_kvx  = (long)65 * 288;
  const long s_qpc  = (long)1024 * 288;

  // phase A: kv accumulation over 4 n-chunks
  for (int c = 0; c < 4; ++c) {
    const long co = (long)c * 1024 * 1024;
    gemm_nt<2><<<dim3(3, 8, 64), 256, 0, stream>>>(
        projb, 64, 0, 0, Kb + co, 1024, sA_bh, 64, chunk, 1024, 16 * s_kptc,
        s_kptc, 288, 1024, 64, nullptr);
    build_vtc<<<dim3(16, 64), 256, 0, stream>>>(Vb, vtc, c);
    gemm_nt<6><<<dim3(1, 3, 64), 256, 0, stream>>>(
        vtc, 1024, 16 * s_vtc, s_vtc, chunk, 1024, 16 * s_kptc, s_kptc, kvxf,
        288, 16 * s_kvx, s_kvx, 65, 288, 1024, nullptr);
  }
  finalize_kvx<<<(1198080 + 255) / 256, 256, 0, stream>>>(kvxf, kvxb, 1198080);

  // phase B: qp + attention output per chunk
  for (int c = 0; c < 4; ++c) {
    const long co = (long)c * 1024 * 1024;
    gemm_nt<1><<<dim3(8, 3, 64), 256, 0, stream>>>(
        Qb + co, 1024, sA_bh, 64, projb, 64, 0, 0, chunk, 288, 16 * s_qpc,
        s_qpc, 1024, 288, 64, nullptr);
    gemm_nt<4><<<dim3(8, 1, 64), 256, 0, stream>>>(
        chunk, 288, 16 * s_qpc, s_qpc, kvxb, 288, 16 * s_kvx, s_kvx,
        outm + co, 1024, sA_bh, 64, 1024, 65, 288, nullptr);
  }

  // S5: out(f32) = outm . wot^T + bo   (256^2 pipeline GEMM, EPI5)
  // Mtiles=64, Ntiles=4 (N=1024), grid 256 (%8==0)
  gemm256<5><<<256, 512, 0, stream>>>(outm, 1024, wot, 1024, out, 1024, 64, 4,
                                      1024, bo);
}

// Round 2
// 395.331 us; speedup vs baseline: 2.1149x; 1.7437x over previous
//
#include <hip/hip_runtime.h>
#include <hip/hip_bf16.h>

// ---------------------------------------------------------------------------
// Performer (FAVOR+) attention, MI355X gfx950.  f32 I/O, bf16 MFMA internals.
// R9: phases A and B fused into single kernels (favor_kv / favor_out).
//   prep:  wqkvt(3072x1024)=bf16([Wq|Wk|Wv]^T); wot=bf16(Wo^T); projb padded
//   S1:    [Qb|Kb|Vb](16384x1024 bf16 each) = xb . wqkvt^T   (gemm256 EPI7)
//   favor_kv (grid 64bh x 4slab): per 128-row tile:
//       kp(288x128) = relu(projb . K_tile^T)+eps (rows>=266 -> 0) -> LDS
//       vt(80x128)  = [V_tile^T ; ones ; zeros]                  -> LDS
//       kvxT(288x80) += kp . vt^T   (f32 regs, accumulated over 1024 rows)
//     -> kvp partial [slab][bh][288][80] f32
//   finalize_kvx2: kvxb[bh][80][288] bf16 = transpose(sum_slab kvp)
//   favor_out (grid 64bh x 8): per 128-row subtile:
//       qp(128x288) = relu(Q_tile . projb^T)+eps (cols>=266 -> 0) -> LDS
//       out(128x80) = qp . kvxb^T ; /denom(col 64); merged-head bf16 store
//   S5:    out(f32) = outm . wot^T + bo (gemm256 EPI5)
// All LDS tiles use the gemm256 16B-granule XOR swizzle (pre-swizzled
// global_load_lds sources; same ds_read pattern -> 0 bank conflicts in R8).
// Aliases: xb==kvp/kvxb region (dead after S1); outm==Kb (dead after A).
// ---------------------------------------------------------------------------

typedef __bf16 bf16x8 __attribute__((ext_vector_type(8)));
typedef unsigned short u16x8 __attribute__((ext_vector_type(8)));
typedef float  f32x4  __attribute__((ext_vector_type(4)));

#define EPS_F 1e-3f

__device__ __forceinline__ void gld16(const void* g, void* l) {
  __builtin_amdgcn_global_load_lds(
      (const __attribute__((address_space(1))) void*)g,
      (__attribute__((address_space(3))) void*)l, 16, 0, 0);
}

// ---------------------------------------------------------------------------
// gemm256: unchanged from R8 (verified).  256x256 tile, BK=64, 8 waves,
// counted vmcnt(8) across raw barriers, XOR-16B swizzle, XCD block swizzle.
// ---------------------------------------------------------------------------
template <int EPI>
__global__ void __launch_bounds__(512, 2)
gemm256(const __hip_bfloat16* __restrict__ A, long lda,
        const __hip_bfloat16* __restrict__ Bt, long ldb,
        void* __restrict__ Cp, long ldc,
        int Mtiles, int Ntiles, int K, const float* __restrict__ bias) {
  __shared__ __align__(16) char sm[131072];

  const int tid  = threadIdx.x;
  const int lane = tid & 63;
  const int wave = tid >> 6;   // 0..7
  const int wm   = wave >> 2;  // 0..1
  const int wn   = wave & 3;   // 0..3
  const int quad = lane >> 4;
  const int l15  = lane & 15;

  const int nwg = Mtiles * Ntiles;
  const int cpx = nwg >> 3;
  const int bid = blockIdx.x;
  const int wid = (bid & 7) * cpx + (bid >> 3);
  const int nt  = wid / Mtiles;
  const int mt  = wid - nt * Mtiles;
  const long m0 = (long)mt * 256;
  const long n0 = (long)nt * 256;

  const int srow = tid >> 3;
  const int sg   = (tid & 7) ^ (srow & 7);
  const __hip_bfloat16* aS = A  + (m0 + srow) * lda + sg * 8;
  const __hip_bfloat16* bS = Bt + (n0 + srow) * ldb + sg * 8;
  char* smc = (char*)sm;
  const int ldsOff = tid * 16;

  const int aRowB = (wm * 128 + l15) * 128;
  const int bRowB = 32768 + (wn * 64 + l15) * 128;
  const int sw    = (l15 & 7) << 4;
  const int cx0   = (quad * 16) ^ sw;
  const int cx1   = (64 + quad * 16) ^ sw;

  f32x4 acc[8][4] = {};

#define STAGE256(pp, kk)                                                     \
  {                                                                          \
    char* ab = smc + (pp) * 65536;                                           \
    _Pragma("unroll") for (int i = 0; i < 4; ++i) {                          \
      gld16(aS + (long)i * 64 * lda + (kk), ab + i * 8192 + ldsOff);         \
      gld16(bS + (long)i * 64 * ldb + (kk), ab + 32768 + i * 8192 + ldsOff); \
    }                                                                        \
  }

  const int NT = K >> 6;
  STAGE256(0, 0)
  STAGE256(1, 64)
  asm volatile("s_waitcnt vmcnt(8)" ::: "memory");
  __builtin_amdgcn_s_barrier();
  asm volatile("" ::: "memory");

  int p = 0;
  for (int t = 0; t < NT; ++t) {
    const char* base = smc + p * 65536;
    bf16x8 bfr[4][2];
#pragma unroll
    for (int jt = 0; jt < 4; ++jt) {
      bfr[jt][0] = *(const bf16x8*)(base + bRowB + jt * 2048 + cx0);
      bfr[jt][1] = *(const bf16x8*)(base + bRowB + jt * 2048 + cx1);
    }
    __builtin_amdgcn_s_setprio(1);
#pragma unroll
    for (int ih = 0; ih < 2; ++ih) {
      bf16x8 af[4][2];
#pragma unroll
      for (int it = 0; it < 4; ++it) {
        af[it][0] = *(const bf16x8*)(base + aRowB + (ih * 4 + it) * 2048 + cx0);
        af[it][1] = *(const bf16x8*)(base + aRowB + (ih * 4 + it) * 2048 + cx1);
      }
#pragma unroll
      for (int it = 0; it < 4; ++it)
#pragma unroll
        for (int jt = 0; jt < 4; ++jt) {
          acc[ih * 4 + it][jt] = __builtin_amdgcn_mfma_f32_16x16x32_bf16(
              af[it][0], bfr[jt][0], acc[ih * 4 + it][jt], 0, 0, 0);
          acc[ih * 4 + it][jt] = __builtin_amdgcn_mfma_f32_16x16x32_bf16(
              af[it][1], bfr[jt][1], acc[ih * 4 + it][jt], 0, 0, 0);
        }
    }
    __builtin_amdgcn_s_setprio(0);
    __builtin_amdgcn_s_barrier();
    asm volatile("" ::: "memory");
    if (t + 2 < NT) {
      STAGE256(p, (long)(t + 2) * 64)
      asm volatile("s_waitcnt vmcnt(8)" ::: "memory");
    } else {
      asm volatile("s_waitcnt vmcnt(0)" ::: "memory");
    }
    __builtin_amdgcn_s_barrier();
    asm volatile("" ::: "memory");
    p ^= 1;
  }
#undef STAGE256

  if constexpr (EPI == 7) {
    __hip_bfloat16* Cb = (__hip_bfloat16*)Cp;
    const long slab  = (n0 >> 10) * 16777216;
    const long ncol0 = (n0 & 1023) + wn * 64 + l15;
#pragma unroll
    for (int it = 0; it < 8; ++it) {
#pragma unroll
      for (int i = 0; i < 4; ++i) {
        const long gm = m0 + wm * 128 + it * 16 + quad * 4 + i;
        __hip_bfloat16* rowp = Cb + slab + gm * 1024 + ncol0;
#pragma unroll
        for (int jt = 0; jt < 4; ++jt)
          rowp[jt * 16] = (__hip_bfloat16)acc[it][jt][i];
      }
    }
  } else if constexpr (EPI == 5) {
    float* Cf = (float*)Cp;
    float bv[4];
#pragma unroll
    for (int jt = 0; jt < 4; ++jt)
      bv[jt] = bias[n0 + wn * 64 + jt * 16 + l15];
#pragma unroll
    for (int it = 0; it < 8; ++it) {
#pragma unroll
      for (int i = 0; i < 4; ++i) {
        const long gm = m0 + wm * 128 + it * 16 + quad * 4 + i;
        float* rowp = Cf + gm * ldc + n0 + wn * 64 + l15;
#pragma unroll
        for (int jt = 0; jt < 4; ++jt)
          rowp[jt * 16] = acc[it][jt][i] + bv[jt];
      }
    }
  }
}

// ---------------------------------------------------------------------------
// favor_kv: fused kp = relu(projb.K^T)+eps ; kvxT(288x80) += kp . [V;1]^T
// grid = 256 (bh = x&63, slab = x>>6), 512 threads, 8 waves.
// LDS: Kt[128 rows x 128B] | Pj[288 x 128B] | KP[288 x 256B] | VT[80 x 256B]
// Swizzles (all on within-row byte offset, 16-aligned units):
//   Kt/Pj: ^((row&7)<<4)   KP: ^((r&7)<<4)   VT: ^(((d&7)^((d>>3)&7))<<4)
// ---------------------------------------------------------------------------
__global__ void __launch_bounds__(512, 2)
favor_kv(const __hip_bfloat16* __restrict__ Kb,
         const __hip_bfloat16* __restrict__ Vb,
         const __hip_bfloat16* __restrict__ projb_g,
         float* __restrict__ kvp) {
  __shared__ __align__(16) char sm[147456];
  char* Kt = sm;
  char* Pj = sm + 16384;
  char* KP = sm + 53248;
  char* VT = sm + 126976;

  const int tid  = threadIdx.x;
  const int lane = tid & 63;
  const int wave = tid >> 6;
  const int quad = lane >> 4;
  const int l15  = lane & 15;
  const int swL  = (l15 & 7) << 4;

  const int bh   = blockIdx.x & 63;
  const int slab = blockIdx.x >> 6;  // 0..3
  const int b    = bh >> 4, h = bh & 15;
  const long rowbase = (long)b * 4096 + (long)slab * 1024;

  // stage projb (288 rows x 8 granules, pre-swizzled source)
  for (int p = 0; p < 5; ++p) {
    const int idx = p * 512 + tid;
    if (idx < 2304) {
      const int r = idx >> 3, g = (idx & 7) ^ (r & 7);
      gld16(projb_g + r * 64 + g * 8, Pj + p * 8192 + tid * 16);
    }
  }
  // init VT rows 64..79 once: row 64 = ones, rows 65..79 = zeros.
  // (constant rows: swizzle-invariant, write linear)
  {
    unsigned short* vth = (unsigned short*)(VT + 64 * 256);
    const unsigned short one_bf = 0x3F80;
    for (int i = tid; i < 2048; i += 512) vth[i] = (i < 128) ? one_bf : 0;
  }

  // GEMM1 tiling: 4M x 2N (M=128 n: A=K_tile, N=288 r: B=projb)
  const int wm1 = wave & 3;   // n-base wm1*32 (2 frags)
  const int wn1 = wave >> 2;  // r-base wn1*144 (9 frags)
  // GEMM2: frag-rows fr = wave + 8j (j < nJ); N=80 (5 frags)
  const int nJ = (wave < 2) ? 3 : 2;

  f32x4 acc2[3][5] = {};

  for (int t = 0; t < 8; ++t) {
    const long n0 = (long)t * 128;
    __syncthreads();  // (1) prev-tile KP/VT/Kt reads complete
    // stage K_tile (128 rows x 8 granules, pre-swizzled source)
    {
      const int r = tid >> 3, g = (tid & 7) ^ (r & 7);
      gld16(Kb + (rowbase + n0 + r) * 1024 + h * 64 + g * 8, Kt + tid * 16);
      const int r2 = r + 64, g2 = (tid & 7) ^ (r2 & 7);
      gld16(Kb + (rowbase + n0 + r2) * 1024 + h * 64 + g2 * 8,
            Kt + 8192 + tid * 16);
    }
    // load V rows to regs (raw bits)
    u16x8 v0, v1;
    {
      const int nl = tid >> 3, seg = tid & 7;
      v0 = *(const u16x8*)(Vb + (rowbase + n0 + nl) * 1024 + h * 64 + seg * 8);
      v1 = *(const u16x8*)(Vb + (rowbase + n0 + 64 + nl) * 1024 + h * 64 +
                           seg * 8);
    }
    __syncthreads();  // (2) Kt valid (vmcnt drained), V in regs
    // write VT rows 0..63 = V^T (b16 scatter, swizzled)
    {
      const int nl = tid >> 3, seg = tid & 7;
#pragma unroll
      for (int j = 0; j < 8; ++j) {
        const int d = seg * 8 + j;
        const int s = ((d & 7) ^ ((d >> 3) & 7)) << 4;
        *(unsigned short*)(VT + d * 256 + ((nl * 2) ^ s)) = v0[j];
        *(unsigned short*)(VT + d * 256 + (((nl + 64) * 2) ^ s)) = v1[j];
      }
    }
    // GEMM1: kp = K_tile . projb^T
    f32x4 acc1[2][9] = {};
#pragma unroll
    for (int ks = 0; ks < 2; ++ks) {
      const int cb = ks * 64 + quad * 16;
      bf16x8 af[2];
#pragma unroll
      for (int fm = 0; fm < 2; ++fm)
        af[fm] = *(const bf16x8*)(Kt + (wm1 * 32 + fm * 16 + l15) * 128 +
                                  (cb ^ swL));
      bf16x8 bfr[9];
#pragma unroll
      for (int fn = 0; fn < 9; ++fn)
        bfr[fn] = *(const bf16x8*)(Pj + (wn1 * 144 + fn * 16 + l15) * 128 +
                                   (cb ^ swL));
#pragma unroll
      for (int fm = 0; fm < 2; ++fm)
#pragma unroll
        for (int fn = 0; fn < 9; ++fn)
          acc1[fm][fn] = __builtin_amdgcn_mfma_f32_16x16x32_bf16(
              af[fm], bfr[fn], acc1[fm][fn], 0, 0, 0);
    }
    // epilogue: relu+eps (r<266 else 0), pack 4 n-consecutive -> KP[r][n]
#pragma unroll
    for (int fm = 0; fm < 2; ++fm) {
      const int nb = (wm1 * 32 + fm * 16 + quad * 4) * 2;  // byte base
#pragma unroll
      for (int fn = 0; fn < 9; ++fn) {
        const int r = wn1 * 144 + fn * 16 + l15;
        const bool ok = (r < 266);
        union { __hip_bfloat16 hh[4]; uint2 u; } pk;
#pragma unroll
        for (int ii = 0; ii < 4; ++ii) {
          float v = acc1[fm][fn][ii];
          v = ok ? (fmaxf(v, 0.f) + EPS_F) : 0.f;
          pk.hh[ii] = (__hip_bfloat16)v;
        }
        *(uint2*)(KP + r * 256 + (nb ^ ((r & 7) << 4))) = pk.u;
      }
    }
    __syncthreads();  // (3) KP + VT visible; all GEMM1 reads done
    // GEMM2: kvxT(288x80) += kp . vt^T   (K = 128 n)
#pragma unroll
    for (int ks = 0; ks < 4; ++ks) {
      const int cb = ks * 64 + quad * 16;
      bf16x8 bfr[5];
#pragma unroll
      for (int fd = 0; fd < 5; ++fd) {
        const int d = fd * 16 + l15;
        const int s = ((d & 7) ^ ((d >> 3) & 7)) << 4;
        bfr[fd] = *(const bf16x8*)(VT + d * 256 + (cb ^ s));
      }
#pragma unroll
      for (int j = 0; j < 3; ++j) {
        if (j < nJ) {
          const int r = (wave + 8 * j) * 16 + l15;
          const bf16x8 af =
              *(const bf16x8*)(KP + r * 256 + (cb ^ ((r & 7) << 4)));
#pragma unroll
          for (int fd = 0; fd < 5; ++fd)
            acc2[j][fd] = __builtin_amdgcn_mfma_f32_16x16x32_bf16(
                af, bfr[fd], acc2[j][fd], 0, 0, 0);
        }
      }
    }
  }
  // store partial kvp[blockIdx][288][80] f32
  float* dst = kvp + (long)blockIdx.x * 23040;
#pragma unroll
  for (int j = 0; j < 3; ++j) {
    if (j < nJ) {
      const int rb = (wave + 8 * j) * 16 + quad * 4;
#pragma unroll
      for (int fd = 0; fd < 5; ++fd) {
        const int d = fd * 16 + l15;
#pragma unroll
        for (int ii = 0; ii < 4; ++ii)
          dst[(long)(rb + ii) * 80 + d] = acc2[j][fd][ii];
      }
    }
  }
}

// kvxb[bh][d][r] bf16 = sum_slab kvp[slab][bh][r][d]
__global__ void __launch_bounds__(256)
finalize_kvx2(const float* __restrict__ kvp,
              __hip_bfloat16* __restrict__ kvxb) {
  __shared__ float lds_f[23040];
  const int bh = blockIdx.x, t = threadIdx.x;
  for (int p = 0; p < 90; ++p) {
    const int idx = p * 256 + t;
    float s = 0.f;
#pragma unroll
    for (int sl = 0; sl < 4; ++sl)
      s += kvp[(long)(sl * 64 + bh) * 23040 + idx];
    lds_f[idx] = s;
  }
  __syncthreads();
  for (int p = 0; p < 90; ++p) {
    const int idx = p * 256 + t;
    const int d = idx / 288, r = idx % 288;
    kvxb[(long)bh * 23040 + idx] = (__hip_bfloat16)lds_f[r * 80 + d];
  }
}

// ---------------------------------------------------------------------------
// favor_out: qp = relu(Q.projb^T)+eps ; out = (qp . kvxb^T)/denom, merged
// grid = 512 (bh = x>>3, rowblock = x&7 -> 512 rows), 512 threads.
// LDS: Pj[288x128B swz] | KX[80 x 592B] | QP[128 x 592B] (Q_tile + Dsh alias)
// ---------------------------------------------------------------------------
__global__ void __launch_bounds__(512, 2)
favor_out(const __hip_bfloat16* __restrict__ Qb,
          const __hip_bfloat16* __restrict__ kvxb_g,
          const __hip_bfloat16* __restrict__ projb_g,
          __hip_bfloat16* __restrict__ outm) {
  __shared__ __align__(16) char sm[160000];
  char* Pj = sm;
  char* KX = sm + 36864;
  char* QP = sm + 84224;

  const int tid  = threadIdx.x;
  const int lane = tid & 63;
  const int wave = tid >> 6;
  const int quad = lane >> 4;
  const int l15  = lane & 15;
  const int swL  = (l15 & 7) << 4;

  const int bh  = blockIdx.x >> 3;
  const int rb8 = blockIdx.x & 7;
  const int b = bh >> 4, h = bh & 15;
  const long rowbase = (long)b * 4096 + (long)rb8 * 512;

  // stage projb (pre-swizzled source)
  for (int p = 0; p < 5; ++p) {
    const int idx = p * 512 + tid;
    if (idx < 2304) {
      const int r = idx >> 3, g = (idx & 7) ^ (r & 7);
      gld16(projb_g + r * 64 + g * 8, Pj + p * 8192 + tid * 16);
    }
  }
  // reg-stage kvxb -> KX (rows padded 288->296 elems; pad never read)
  {
    const __hip_bfloat16* src = kvxb_g + (long)bh * 23040;
#pragma unroll
    for (int p = 0; p < 6; ++p) {
      const int idx = p * 512 + tid;
      if (idx < 2880) {
        const int d = idx / 36, g = idx % 36;
        const bf16x8 v = *(const bf16x8*)(src + d * 288 + g * 8);
        *(bf16x8*)(KX + d * 592 + g * 16) = v;
      }
    }
  }
  __syncthreads();

  // GEMM1 tiling: 2M x 4N (M=288 r: A=projb, N=128 n: B=Q_tile)
  const int wm1 = wave >> 2;  // r-base wm1*144 (9 frags)
  const int wn1 = wave & 3;   // n-base wn1*32  (2 frags)

  for (int s = 0; s < 4; ++s) {
    const long n0 = (long)s * 128;
    // stage Q_tile into QP base (linear + swz source); prev readers done
    {
      const int r = tid >> 3, g = (tid & 7) ^ (r & 7);
      gld16(Qb + (rowbase + n0 + r) * 1024 + h * 64 + g * 8, QP + tid * 16);
      const int r2 = r + 64, g2 = (tid & 7) ^ (r2 & 7);
      gld16(Qb + (rowbase + n0 + r2) * 1024 + h * 64 + g2 * 8,
            QP + 8192 + tid * 16);
    }
    __syncthreads();  // Q visible
    f32x4 acc1[9][2] = {};
#pragma unroll
    for (int ks = 0; ks < 2; ++ks) {
      const int cb = ks * 64 + quad * 16;
      bf16x8 bfr[2];
#pragma unroll
      for (int fn = 0; fn < 2; ++fn)
        bfr[fn] = *(const bf16x8*)(QP + (wn1 * 32 + fn * 16 + l15) * 128 +
                                   (cb ^ swL));
      bf16x8 af[9];
#pragma unroll
      for (int fm = 0; fm < 9; ++fm)
        af[fm] = *(const bf16x8*)(Pj + (wm1 * 144 + fm * 16 + l15) * 128 +
                                  (cb ^ swL));
#pragma unroll
      for (int fm = 0; fm < 9; ++fm)
#pragma unroll
        for (int fn = 0; fn < 2; ++fn)
          acc1[fm][fn] = __builtin_amdgcn_mfma_f32_16x16x32_bf16(
              af[fm], bfr[fn], acc1[fm][fn], 0, 0, 0);
    }
    __syncthreads();  // all Q reads done before qp overwrites Q bytes
    // epilogue: relu+eps (per-element r<266), pack 4 r-consecutive -> QP[n][r]
#pragma unroll
    for (int fm = 0; fm < 9; ++fm) {
      const int r0 = wm1 * 144 + fm * 16 + quad * 4;
#pragma unroll
      for (int fn = 0; fn < 2; ++fn) {
        const int n = wn1 * 32 + fn * 16 + l15;
        union { __hip_bfloat16 hh[4]; uint2 u; } pk;
#pragma unroll
        for (int ii = 0; ii < 4; ++ii) {
          float v = acc1[fm][fn][ii];
          v = (r0 + ii < 266) ? (fmaxf(v, 0.f) + EPS_F) : 0.f;
          pk.hh[ii] = (__hip_bfloat16)v;
        }
        *(uint2*)(QP + n * 592 + r0 * 2) = pk.u;
      }
    }
    __syncthreads();  // qp visible
    // GEMM2: out(128x80) = qp . kvxb^T  (K=288)
    f32x4 acc2[5] = {};
#pragma unroll
    for (int ks = 0; ks < 9; ++ks) {
      const int cb = ks * 64 + quad * 16;
      const bf16x8 af = *(const bf16x8*)(QP + (wave * 16 + l15) * 592 + cb);
      bf16x8 bfr[5];
#pragma unroll
      for (int fd = 0; fd < 5; ++fd)
        bfr[fd] = *(const bf16x8*)(KX + (fd * 16 + l15) * 592 + cb);
#pragma unroll
      for (int fd = 0; fd < 5; ++fd)
        acc2[fd] = __builtin_amdgcn_mfma_f32_16x16x32_bf16(af, bfr[fd],
                                                           acc2[fd], 0, 0, 0);
    }
    __syncthreads();  // all qp reads done -> Dsh may alias QP base
    float* Dsh = (float*)QP;
    if (l15 == 0) {
#pragma unroll
      for (int ii = 0; ii < 4; ++ii)
        Dsh[wave * 16 + quad * 4 + ii] = acc2[4][ii];
    }
    __syncthreads();  // Dsh visible
#pragma unroll
    for (int ii = 0; ii < 4; ++ii) {
      const int nloc = wave * 16 + quad * 4 + ii;
      const float den = Dsh[nloc];
      const float dinv = (den > 1e-30f) ? (1.f / den) : 0.f;
      __hip_bfloat16* rowp = outm + (rowbase + n0 + nloc) * 1024 + h * 64;
#pragma unroll
      for (int fd = 0; fd < 4; ++fd)
        rowp[fd * 16 + l15] = (__hip_bfloat16)(acc2[fd][ii] * dinv);
    }
    __syncthreads();  // Dsh reads done before next Q stage
  }
}

// xb = bf16(x), 8 elements/thread
__global__ void cvt_x(const float* __restrict__ x,
                      __hip_bfloat16* __restrict__ xb) {
  const long i = ((long)blockIdx.x * 256 + threadIdx.x) * 8;
  const float4 f0 = *(const float4*)(x + i);
  const float4 f1 = *(const float4*)(x + i + 4);
  union { __hip_bfloat16 h[8]; uint4 u; } r;
  r.h[0] = (__hip_bfloat16)f0.x; r.h[1] = (__hip_bfloat16)f0.y;
  r.h[2] = (__hip_bfloat16)f0.z; r.h[3] = (__hip_bfloat16)f0.w;
  r.h[4] = (__hip_bfloat16)f1.x; r.h[5] = (__hip_bfloat16)f1.y;
  r.h[6] = (__hip_bfloat16)f1.z; r.h[7] = (__hip_bfloat16)f1.w;
  *(uint4*)(xb + i) = r.u;
}

// all 4 weight transposes in one launch: z in 0..3 picks src/dst.
__global__ void transpose_w4(const float* __restrict__ s0,
                             const float* __restrict__ s1,
                             const float* __restrict__ s2,
                             const float* __restrict__ s3,
                             __hip_bfloat16* __restrict__ dq,
                             __hip_bfloat16* __restrict__ dwo) {
  __shared__ float t[32][33];
  const int z = blockIdx.z;
  const float* src = (z == 0) ? s0 : (z == 1) ? s1 : (z == 2) ? s2 : s3;
  __hip_bfloat16* dst = (z < 3) ? (dq + (long)z * 1048576) : dwo;
  const int k0 = blockIdx.x * 32, n0 = blockIdx.y * 32;
  const int tx = threadIdx.x & 31, ty = threadIdx.x >> 5;
#pragma unroll
  for (int i = 0; i < 4; ++i)
    t[ty + i * 8][tx] = src[(long)(k0 + ty + i * 8) * 1024 + n0 + tx];
  __syncthreads();
#pragma unroll
  for (int i = 0; i < 4; ++i)
    dst[(long)(n0 + ty + i * 8) * 1024 + k0 + tx] =
        (__hip_bfloat16)t[tx][ty + i * 8];
}

// projb (288x64 bf16): rows<266 = bf16(proj), rows 266..287 exact zero.
__global__ void prep_proj(const float* __restrict__ proj,
                          __hip_bfloat16* __restrict__ projb) {
  const int i = blockIdx.x * 256 + threadIdx.x;
  if (i < 288 * 64) {
    const int r = i >> 6;
    __hip_bfloat16 v = (__hip_bfloat16)0.f;
    if (r < 266) v = (__hip_bfloat16)proj[i];
    projb[i] = v;
  }
}

// ---------------------------------------------------------------------------
extern "C" void kernel_launch(void* const* d_in, const int* in_sizes, int n_in,
                              void* d_out, int out_size, void* d_ws,
                              size_t ws_size, hipStream_t stream) {
  const float* x    = (const float*)d_in[0];
  const float* Wq   = (const float*)d_in[1];
  const float* Wk   = (const float*)d_in[2];
  const float* Wv   = (const float*)d_in[3];
  const float* Wo   = (const float*)d_in[4];
  const float* bo   = (const float*)d_in[5];
  const float* proj = (const float*)d_in[6];
  float* out = (float*)d_out;
  char* ws = (char*)d_ws;

  // ws layout (bytes); total 135,630,848 (< 162.5 MB previously proven)
  constexpr long o_wqkvt = 0;            // 6,291,456
  constexpr long o_wot   = 6291456;      // 2,097,152
  constexpr long o_projb = 8388608;      // 36,864
  constexpr long o_Qb    = 8425472;      // 33,554,432
  constexpr long o_Kb    = 41979904;     // 33,554,432 (alias outm)
  constexpr long o_Vb    = 75534336;     // 33,554,432
  constexpr long o_xb    = 109088768;    // 33,554,432 (alias kvp/kvxb)
  constexpr long o_kvp   = 109088768;    // 4*64*23040*4 = 23,592,960
  constexpr long o_kvxb  = 132681728;    // 64*23040*2   =  2,949,120

  __hip_bfloat16* wqkvt = (__hip_bfloat16*)(ws + o_wqkvt);
  __hip_bfloat16* wot   = (__hip_bfloat16*)(ws + o_wot);
  __hip_bfloat16* projb = (__hip_bfloat16*)(ws + o_projb);
  __hip_bfloat16* Qb    = (__hip_bfloat16*)(ws + o_Qb);
  __hip_bfloat16* Kb    = (__hip_bfloat16*)(ws + o_Kb);
  __hip_bfloat16* Vb    = (__hip_bfloat16*)(ws + o_Vb);
  __hip_bfloat16* xb    = (__hip_bfloat16*)(ws + o_xb);
  float*          kvp   = (float*)(ws + o_kvp);
  __hip_bfloat16* kvxb  = (__hip_bfloat16*)(ws + o_kvxb);
  __hip_bfloat16* outm  = Kb;  // alias: Kb dead after favor_kv

  // prep
  cvt_x<<<8192, 256, 0, stream>>>(x, xb);
  transpose_w4<<<dim3(32, 32, 4), 256, 0, stream>>>(Wq, Wk, Wv, Wo, wqkvt,
                                                    wot);
  prep_proj<<<72, 256, 0, stream>>>(proj, projb);

  // S1 fused: [Qb|Kb|Vb] = xb . wqkvt^T  (256^2 pipeline GEMM, EPI7)
  gemm256<7><<<768, 512, 0, stream>>>(xb, 1024, wqkvt, 1024, Qb, 0, 64, 12,
                                      1024, nullptr);

  // phase A fused: kvp partials, then reduce+transpose to kvxb
  favor_kv<<<256, 512, 0, stream>>>(Kb, Vb, projb, kvp);
  finalize_kvx2<<<64, 256, 0, stream>>>(kvp, kvxb);

  // phase B fused: outm = (relu(Q.projb^T)+eps) . kvxb^T / denom, merged
  favor_out<<<512, 512, 0, stream>>>(Qb, kvxb, projb, outm);

  // S5: out(f32) = outm . wot^T + bo  (256^2 pipeline GEMM, EPI5)
  gemm256<5><<<256, 512, 0, stream>>>(outm, 1024, wot, 1024, out, 1024, 64, 4,
                                      1024, bo);
}

// Round 3
// 387.423 us; speedup vs baseline: 2.1581x; 1.0204x over previous
//
#include <hip/hip_runtime.h>
#include <hip/hip_bf16.h>

// ---------------------------------------------------------------------------
// Performer (FAVOR+) attention, MI355X gfx950.  f32 I/O, bf16 MFMA internals.
// R10: (1) gemm256 block->tile mapping made XCD-local (each XCD owns a
// contiguous 8-Mtile band; walked in 8mt x 4nt groups of 32 = concurrent
// blocks/XCD -> A+B working set ~6MB ~ L2) -- pure index remap, inner loop
// untouched.  (2) favor_kv / favor_out converted from __syncthreads (which
// drains vmcnt(0), exposing full HBM latency per tile) to the gemm256
// raw-barrier + counted-wait idiom, with next-tile K/V/Q prefetch issued
// during GEMM2 so the latency hides under compute.  MFMA/epilogue bodies
// are byte-identical to the R9-verified code.
//   prep:  wqkvt(3072x1024)=bf16([Wq|Wk|Wv]^T); wot=bf16(Wo^T); projb padded
//   S1:    [Qb|Kb|Vb](16384x1024 bf16 each) = xb . wqkvt^T   (gemm256 EPI7)
//   favor_kv (grid 64bh x 4slab): per 128-row tile:
//       kp(288x128) = relu(projb . K_tile^T)+eps (rows>=266 -> 0) -> LDS
//       vt(80x128)  = [V_tile^T ; ones ; zeros]                  -> LDS
//       kvxT(288x80) += kp . vt^T   (f32 regs, accumulated over 1024 rows)
//   finalize_kvx2: kvxb[bh][80][288] bf16 = transpose(sum_slab kvp)
//   favor_out (grid 64bh x 8): per 128-row subtile:
//       qp(128x288) = relu(Q_tile . projb^T)+eps (cols>=266 -> 0) -> LDS
//       out(128x80) = qp . kvxb^T ; /denom(col 64); merged-head bf16 store
//   S5:    out(f32) = outm . wot^T + bo (gemm256 EPI5)
// Aliases: xb==kvp/kvxb region (dead after S1); outm==Kb (dead after A).
// ---------------------------------------------------------------------------

typedef __bf16 bf16x8 __attribute__((ext_vector_type(8)));
typedef unsigned short u16x8 __attribute__((ext_vector_type(8)));
typedef float  f32x4  __attribute__((ext_vector_type(4)));

#define EPS_F 1e-3f

__device__ __forceinline__ void gld16(const void* g, void* l) {
  __builtin_amdgcn_global_load_lds(
      (const __attribute__((address_space(1))) void*)g,
      (__attribute__((address_space(3))) void*)l, 16, 0, 0);
}

// ---------------------------------------------------------------------------
// gemm256: 256x256 tile, BK=64, 8 waves, counted vmcnt(8) across raw
// barriers, XOR-16B swizzle.  R10: XCD-local rectangular block mapping.
// Requires M%256==0, N%256==0, K%64==0, Mtiles%8==0, Ntiles%4==0.
// ---------------------------------------------------------------------------
template <int EPI>
__global__ void __launch_bounds__(512, 2)
gemm256(const __hip_bfloat16* __restrict__ A, long lda,
        const __hip_bfloat16* __restrict__ Bt, long ldb,
        void* __restrict__ Cp, long ldc,
        int Mtiles, int Ntiles, int K, const float* __restrict__ bias) {
  __shared__ __align__(16) char sm[131072];

  const int tid  = threadIdx.x;
  const int lane = tid & 63;
  const int wave = tid >> 6;   // 0..7
  const int wm   = wave >> 2;  // 0..1
  const int wn   = wave & 3;   // 0..3
  const int quad = lane >> 4;
  const int l15  = lane & 15;

  // XCD-local mapping: XCD x owns mt in [x*Mx, (x+1)*Mx); within its chunk,
  // blocks walk 4-nt groups of (Mx x 4) = 32 blocks (~ concurrent per XCD)
  // so the live working set is A 4MB + B 2MB ~ one L2.
  const int bid = blockIdx.x;
  const int Mx  = Mtiles >> 3;          // Mtiles per XCD
  const int xcd = bid & 7;
  const int wl  = bid >> 3;             // 0..(Mx*Ntiles)-1
  const int gsz = Mx << 2;              // blocks per nt-group
  const int grp = wl / gsz;
  const int rr  = wl - grp * gsz;
  const int mt  = xcd * Mx + (rr % Mx);
  const int nt  = (grp << 2) + (rr / Mx);
  const long m0 = (long)mt * 256;
  const long n0 = (long)nt * 256;

  const int srow = tid >> 3;
  const int sg   = (tid & 7) ^ (srow & 7);
  const __hip_bfloat16* aS = A  + (m0 + srow) * lda + sg * 8;
  const __hip_bfloat16* bS = Bt + (n0 + srow) * ldb + sg * 8;
  char* smc = (char*)sm;
  const int ldsOff = tid * 16;

  const int aRowB = (wm * 128 + l15) * 128;
  const int bRowB = 32768 + (wn * 64 + l15) * 128;
  const int sw    = (l15 & 7) << 4;
  const int cx0   = (quad * 16) ^ sw;
  const int cx1   = (64 + quad * 16) ^ sw;

  f32x4 acc[8][4] = {};

#define STAGE256(pp, kk)                                                     \
  {                                                                          \
    char* ab = smc + (pp) * 65536;                                           \
    _Pragma("unroll") for (int i = 0; i < 4; ++i) {                          \
      gld16(aS + (long)i * 64 * lda + (kk), ab + i * 8192 + ldsOff);         \
      gld16(bS + (long)i * 64 * ldb + (kk), ab + 32768 + i * 8192 + ldsOff); \
    }                                                                        \
  }

  const int NT = K >> 6;
  STAGE256(0, 0)
  STAGE256(1, 64)
  asm volatile("s_waitcnt vmcnt(8)" ::: "memory");
  __builtin_amdgcn_s_barrier();
  asm volatile("" ::: "memory");

  int p = 0;
  for (int t = 0; t < NT; ++t) {
    const char* base = smc + p * 65536;
    bf16x8 bfr[4][2];
#pragma unroll
    for (int jt = 0; jt < 4; ++jt) {
      bfr[jt][0] = *(const bf16x8*)(base + bRowB + jt * 2048 + cx0);
      bfr[jt][1] = *(const bf16x8*)(base + bRowB + jt * 2048 + cx1);
    }
    __builtin_amdgcn_s_setprio(1);
#pragma unroll
    for (int ih = 0; ih < 2; ++ih) {
      bf16x8 af[4][2];
#pragma unroll
      for (int it = 0; it < 4; ++it) {
        af[it][0] = *(const bf16x8*)(base + aRowB + (ih * 4 + it) * 2048 + cx0);
        af[it][1] = *(const bf16x8*)(base + aRowB + (ih * 4 + it) * 2048 + cx1);
      }
#pragma unroll
      for (int it = 0; it < 4; ++it)
#pragma unroll
        for (int jt = 0; jt < 4; ++jt) {
          acc[ih * 4 + it][jt] = __builtin_amdgcn_mfma_f32_16x16x32_bf16(
              af[it][0], bfr[jt][0], acc[ih * 4 + it][jt], 0, 0, 0);
          acc[ih * 4 + it][jt] = __builtin_amdgcn_mfma_f32_16x16x32_bf16(
              af[it][1], bfr[jt][1], acc[ih * 4 + it][jt], 0, 0, 0);
        }
    }
    __builtin_amdgcn_s_setprio(0);
    __builtin_amdgcn_s_barrier();
    asm volatile("" ::: "memory");
    if (t + 2 < NT) {
      STAGE256(p, (long)(t + 2) * 64)
      asm volatile("s_waitcnt vmcnt(8)" ::: "memory");
    } else {
      asm volatile("s_waitcnt vmcnt(0)" ::: "memory");
    }
    __builtin_amdgcn_s_barrier();
    asm volatile("" ::: "memory");
    p ^= 1;
  }
#undef STAGE256

  if constexpr (EPI == 7) {
    __hip_bfloat16* Cb = (__hip_bfloat16*)Cp;
    const long slab  = (n0 >> 10) * 16777216;
    const long ncol0 = (n0 & 1023) + wn * 64 + l15;
#pragma unroll
    for (int it = 0; it < 8; ++it) {
#pragma unroll
      for (int i = 0; i < 4; ++i) {
        const long gm = m0 + wm * 128 + it * 16 + quad * 4 + i;
        __hip_bfloat16* rowp = Cb + slab + gm * 1024 + ncol0;
#pragma unroll
        for (int jt = 0; jt < 4; ++jt)
          rowp[jt * 16] = (__hip_bfloat16)acc[it][jt][i];
      }
    }
  } else if constexpr (EPI == 5) {
    float* Cf = (float*)Cp;
    float bv[4];
#pragma unroll
    for (int jt = 0; jt < 4; ++jt)
      bv[jt] = bias[n0 + wn * 64 + jt * 16 + l15];
#pragma unroll
    for (int it = 0; it < 8; ++it) {
#pragma unroll
      for (int i = 0; i < 4; ++i) {
        const long gm = m0 + wm * 128 + it * 16 + quad * 4 + i;
        float* rowp = Cf + gm * ldc + n0 + wn * 64 + l15;
#pragma unroll
        for (int jt = 0; jt < 4; ++jt)
          rowp[jt * 16] = acc[it][jt][i] + bv[jt];
      }
    }
  }
}

// ---------------------------------------------------------------------------
// favor_kv: fused kp = relu(projb.K^T)+eps ; kvxT(288x80) += kp . [V;1]^T
// R10 schedule per tile (raw barriers, no vmcnt(0)-drain stalls):
//   [top] vmcnt(0); barrier        <- K(t) in LDS, V(t) in regs (issued
//                                     one GEMM2 ago -> latency hidden)
//   VT scatter ; GEMM1 ; KP epilogue
//   lgkmcnt(0); barrier            <- KP/VT visible; all Kt reads consumed
//   prefetch K(t+1) (gld_lds, same buffer - safe after barrier) + V(t+1)
//   GEMM2 (accumulate)
// ---------------------------------------------------------------------------
__global__ void __launch_bounds__(512, 2)
favor_kv(const __hip_bfloat16* __restrict__ Kb,
         const __hip_bfloat16* __restrict__ Vb,
         const __hip_bfloat16* __restrict__ projb_g,
         float* __restrict__ kvp) {
  __shared__ __align__(16) char sm[147456];
  char* Kt = sm;
  char* Pj = sm + 16384;
  char* KP = sm + 53248;
  char* VT = sm + 126976;

  const int tid  = threadIdx.x;
  const int lane = tid & 63;
  const int wave = tid >> 6;
  const int quad = lane >> 4;
  const int l15  = lane & 15;
  const int swL  = (l15 & 7) << 4;

  const int bh   = blockIdx.x & 63;
  const int slab = blockIdx.x >> 6;  // 0..3
  const int b    = bh >> 4, h = bh & 15;
  const long rowbase = (long)b * 4096 + (long)slab * 1024;

  // stage projb (288 rows x 8 granules, pre-swizzled source)
  for (int p = 0; p < 5; ++p) {
    const int idx = p * 512 + tid;
    if (idx < 2304) {
      const int r = idx >> 3, g = (idx & 7) ^ (r & 7);
      gld16(projb_g + r * 64 + g * 8, Pj + p * 8192 + tid * 16);
    }
  }
  // init VT rows 64..79 once: row 64 = ones, rows 65..79 = zeros.
  {
    unsigned short* vth = (unsigned short*)(VT + 64 * 256);
    const unsigned short one_bf = 0x3F80;
    for (int i = tid; i < 2048; i += 512) vth[i] = (i < 128) ? one_bf : 0;
  }

  // tile-0 prefetch: K into LDS, V into regs
  const int rS = tid >> 3, gS = (tid & 7) ^ (rS & 7);
  const int rS2 = rS + 64, gS2 = (tid & 7) ^ (rS2 & 7);
  const int nl = tid >> 3, seg = tid & 7;
  gld16(Kb + (rowbase + rS) * 1024 + h * 64 + gS * 8, Kt + tid * 16);
  gld16(Kb + (rowbase + rS2) * 1024 + h * 64 + gS2 * 8, Kt + 8192 + tid * 16);
  u16x8 vc0 = *(const u16x8*)(Vb + (rowbase + nl) * 1024 + h * 64 + seg * 8);
  u16x8 vc1 =
      *(const u16x8*)(Vb + (rowbase + 64 + nl) * 1024 + h * 64 + seg * 8);

  // GEMM1 tiling: 4M x 2N (M=128 n: A=K_tile, N=288 r: B=projb)
  const int wm1 = wave & 3;   // n-base wm1*32 (2 frags)
  const int wn1 = wave >> 2;  // r-base wn1*144 (9 frags)
  // GEMM2: frag-rows fr = wave + 8j (j < nJ); N=80 (5 frags)
  const int nJ = (wave < 2) ? 3 : 2;

  f32x4 acc2[3][5] = {};

  for (int t = 0; t < 8; ++t) {
    asm volatile("s_waitcnt vmcnt(0)" ::: "memory");  // K(t) LDS, V(t) regs
    __builtin_amdgcn_s_barrier();  // all staged; prev GEMM2 reads consumed
    asm volatile("" ::: "memory");
    // write VT rows 0..63 = V^T (b16 scatter, swizzled)
    {
#pragma unroll
      for (int j = 0; j < 8; ++j) {
        const int d = seg * 8 + j;
        const int s = ((d & 7) ^ ((d >> 3) & 7)) << 4;
        *(unsigned short*)(VT + d * 256 + ((nl * 2) ^ s)) = vc0[j];
        *(unsigned short*)(VT + d * 256 + (((nl + 64) * 2) ^ s)) = vc1[j];
      }
    }
    // GEMM1: kp = K_tile . projb^T
    f32x4 acc1[2][9] = {};
#pragma unroll
    for (int ks = 0; ks < 2; ++ks) {
      const int cb = ks * 64 + quad * 16;
      bf16x8 af[2];
#pragma unroll
      for (int fm = 0; fm < 2; ++fm)
        af[fm] = *(const bf16x8*)(Kt + (wm1 * 32 + fm * 16 + l15) * 128 +
                                  (cb ^ swL));
      bf16x8 bfr[9];
#pragma unroll
      for (int fn = 0; fn < 9; ++fn)
        bfr[fn] = *(const bf16x8*)(Pj + (wn1 * 144 + fn * 16 + l15) * 128 +
                                   (cb ^ swL));
#pragma unroll
      for (int fm = 0; fm < 2; ++fm)
#pragma unroll
        for (int fn = 0; fn < 9; ++fn)
          acc1[fm][fn] = __builtin_amdgcn_mfma_f32_16x16x32_bf16(
              af[fm], bfr[fn], acc1[fm][fn], 0, 0, 0);
    }
    // epilogue: relu+eps (r<266 else 0), pack 4 n-consecutive -> KP[r][n]
#pragma unroll
    for (int fm = 0; fm < 2; ++fm) {
      const int nb = (wm1 * 32 + fm * 16 + quad * 4) * 2;  // byte base
#pragma unroll
      for (int fn = 0; fn < 9; ++fn) {
        const int r = wn1 * 144 + fn * 16 + l15;
        const bool ok = (r < 266);
        union { __hip_bfloat16 hh[4]; uint2 u; } pk;
#pragma unroll
        for (int ii = 0; ii < 4; ++ii) {
          float v = acc1[fm][fn][ii];
          v = ok ? (fmaxf(v, 0.f) + EPS_F) : 0.f;
          pk.hh[ii] = (__hip_bfloat16)v;
        }
        *(uint2*)(KP + r * 256 + (nb ^ ((r & 7) << 4))) = pk.u;
      }
    }
    asm volatile("s_waitcnt lgkmcnt(0)" ::: "memory");  // my VT/KP writes done
    __builtin_amdgcn_s_barrier();  // KP/VT visible; all Kt reads consumed
    asm volatile("" ::: "memory");
    // prefetch next tile during GEMM2 (Kt free: all reads consumed)
    if (t < 7) {
      const long n1 = (long)(t + 1) * 128;
      gld16(Kb + (rowbase + n1 + rS) * 1024 + h * 64 + gS * 8, Kt + tid * 16);
      gld16(Kb + (rowbase + n1 + rS2) * 1024 + h * 64 + gS2 * 8,
            Kt + 8192 + tid * 16);
      vc0 = *(const u16x8*)(Vb + (rowbase + n1 + nl) * 1024 + h * 64 +
                            seg * 8);
      vc1 = *(const u16x8*)(Vb + (rowbase + n1 + 64 + nl) * 1024 + h * 64 +
                            seg * 8);
    }
    // GEMM2: kvxT(288x80) += kp . vt^T   (K = 128 n)
#pragma unroll
    for (int ks = 0; ks < 4; ++ks) {
      const int cb = ks * 64 + quad * 16;
      bf16x8 bfr[5];
#pragma unroll
      for (int fd = 0; fd < 5; ++fd) {
        const int d = fd * 16 + l15;
        const int s = ((d & 7) ^ ((d >> 3) & 7)) << 4;
        bfr[fd] = *(const bf16x8*)(VT + d * 256 + (cb ^ s));
      }
#pragma unroll
      for (int j = 0; j < 3; ++j) {
        if (j < nJ) {
          const int r = (wave + 8 * j) * 16 + l15;
          const bf16x8 af =
              *(const bf16x8*)(KP + r * 256 + (cb ^ ((r & 7) << 4)));
#pragma unroll
          for (int fd = 0; fd < 5; ++fd)
            acc2[j][fd] = __builtin_amdgcn_mfma_f32_16x16x32_bf16(
                af, bfr[fd], acc2[j][fd], 0, 0, 0);
        }
      }
    }
  }
  // store partial kvp[blockIdx][288][80] f32
  float* dst = kvp + (long)blockIdx.x * 23040;
#pragma unroll
  for (int j = 0; j < 3; ++j) {
    if (j < nJ) {
      const int rb = (wave + 8 * j) * 16 + quad * 4;
#pragma unroll
      for (int fd = 0; fd < 5; ++fd) {
        const int d = fd * 16 + l15;
#pragma unroll
        for (int ii = 0; ii < 4; ++ii)
          dst[(long)(rb + ii) * 80 + d] = acc2[j][fd][ii];
      }
    }
  }
}

// kvxb[bh][d][r] bf16 = sum_slab kvp[slab][bh][r][d]
__global__ void __launch_bounds__(256)
finalize_kvx2(const float* __restrict__ kvp,
              __hip_bfloat16* __restrict__ kvxb) {
  __shared__ float lds_f[23040];
  const int bh = blockIdx.x, t = threadIdx.x;
  for (int p = 0; p < 90; ++p) {
    const int idx = p * 256 + t;
    float s = 0.f;
#pragma unroll
    for (int sl = 0; sl < 4; ++sl)
      s += kvp[(long)(sl * 64 + bh) * 23040 + idx];
    lds_f[idx] = s;
  }
  __syncthreads();
  for (int p = 0; p < 90; ++p) {
    const int idx = p * 256 + t;
    const int d = idx / 288, r = idx % 288;
    kvxb[(long)bh * 23040 + idx] = (__hip_bfloat16)lds_f[r * 80 + d];
  }
}

// ---------------------------------------------------------------------------
// favor_out: qp = relu(Q.projb^T)+eps ; out = (qp . kvxb^T)/denom, merged
// R10 schedule per subtile (raw barriers; Q(s+1) reg-prefetched during
// GEMM2 of subtile s -> no staging stall):
//   ds_write Q(s) from regs ; lgkmcnt(0) [; vmcnt(0) s==0] ; barrier
//   GEMM1 ; issue Q(s+1) reg loads ; barrier (Q reads consumed)
//   qp epilogue ; lgkmcnt(0) ; barrier
//   GEMM2 ; Dsh write ; lgkmcnt(0) ; barrier ; /denom stores
// Dsh lives in its own 512B slot (no longer aliases the Q bytes).
// ---------------------------------------------------------------------------
__global__ void __launch_bounds__(512, 2)
favor_out(const __hip_bfloat16* __restrict__ Qb,
          const __hip_bfloat16* __restrict__ kvxb_g,
          const __hip_bfloat16* __restrict__ projb_g,
          __hip_bfloat16* __restrict__ outm) {
  __shared__ __align__(16) char sm[160512];
  char* Pj = sm;
  char* KX = sm + 36864;
  char* QP = sm + 84224;                  // 75776 B, ends 160000
  float* Dsh = (float*)(sm + 160000);     // 512 B

  const int tid  = threadIdx.x;
  const int lane = tid & 63;
  const int wave = tid >> 6;
  const int quad = lane >> 4;
  const int l15  = lane & 15;
  const int swL  = (l15 & 7) << 4;

  const int bh  = blockIdx.x >> 3;
  const int rb8 = blockIdx.x & 7;
  const int b = bh >> 4, h = bh & 15;
  const long rowbase = (long)b * 4096 + (long)rb8 * 512;

  // stage projb (pre-swizzled source)
  for (int p = 0; p < 5; ++p) {
    const int idx = p * 512 + tid;
    if (idx < 2304) {
      const int r = idx >> 3, g = (idx & 7) ^ (r & 7);
      gld16(projb_g + r * 64 + g * 8, Pj + p * 8192 + tid * 16);
    }
  }
  // reg-stage kvxb -> KX (rows padded 288->296 elems; pad never read)
  {
    const __hip_bfloat16* src = kvxb_g + (long)bh * 23040;
#pragma unroll
    for (int p = 0; p < 6; ++p) {
      const int idx = p * 512 + tid;
      if (idx < 2880) {
        const int d = idx / 36, g = idx % 36;
        const bf16x8 v = *(const bf16x8*)(src + d * 288 + g * 8);
        *(bf16x8*)(KX + d * 592 + g * 16) = v;
      }
    }
  }
  // Q(0) reg prefetch (same pre-swizzled addresses as the old gld_lds)
  const int rS = tid >> 3, gS = (tid & 7) ^ (rS & 7);
  const int rS2 = rS + 64, gS2 = (tid & 7) ^ (rS2 & 7);
  u16x8 qv0 = *(const u16x8*)(Qb + (rowbase + rS) * 1024 + h * 64 + gS * 8);
  u16x8 qv1 = *(const u16x8*)(Qb + (rowbase + rS2) * 1024 + h * 64 + gS2 * 8);

  // GEMM1 tiling: 2M x 4N (M=288 r: A=projb, N=128 n: B=Q_tile)
  const int wm1 = wave >> 2;  // r-base wm1*144 (9 frags)
  const int wn1 = wave & 3;   // n-base wn1*32  (2 frags)

  for (int s = 0; s < 4; ++s) {
    // write Q(s) into QP base (auto vmcnt wait on qv)
    *(u16x8*)(QP + tid * 16) = qv0;
    *(u16x8*)(QP + 8192 + tid * 16) = qv1;
    asm volatile("s_waitcnt lgkmcnt(0)" ::: "memory");
    if (s == 0) asm volatile("s_waitcnt vmcnt(0)" ::: "memory");  // Pj ready
    __builtin_amdgcn_s_barrier();  // Q visible (+Pj/KX on s==0)
    asm volatile("" ::: "memory");
    f32x4 acc1[9][2] = {};
#pragma unroll
    for (int ks = 0; ks < 2; ++ks) {
      const int cb = ks * 64 + quad * 16;
      bf16x8 bfr[2];
#pragma unroll
      for (int fn = 0; fn < 2; ++fn)
        bfr[fn] = *(const bf16x8*)(QP + (wn1 * 32 + fn * 16 + l15) * 128 +
                                   (cb ^ swL));
      bf16x8 af[9];
#pragma unroll
      for (int fm = 0; fm < 9; ++fm)
        af[fm] = *(const bf16x8*)(Pj + (wm1 * 144 + fm * 16 + l15) * 128 +
                                  (cb ^ swL));
#pragma unroll
      for (int fm = 0; fm < 9; ++fm)
#pragma unroll
        for (int fn = 0; fn < 2; ++fn)
          acc1[fm][fn] = __builtin_amdgcn_mfma_f32_16x16x32_bf16(
              af[fm], bfr[fn], acc1[fm][fn], 0, 0, 0);
    }
    // issue Q(s+1) prefetch; lands during epilogue+GEMM2
    if (s < 3) {
      const long n1 = (long)(s + 1) * 128;
      qv0 = *(const u16x8*)(Qb + (rowbase + n1 + rS) * 1024 + h * 64 + gS * 8);
      qv1 = *(const u16x8*)(Qb + (rowbase + n1 + rS2) * 1024 + h * 64 +
                            gS2 * 8);
    }
    __builtin_amdgcn_s_barrier();  // all waves' Q reads consumed
    asm volatile("" ::: "memory");
    // epilogue: relu+eps (per-element r<266), pack 4 r-consecutive -> QP[n][r]
#pragma unroll
    for (int fm = 0; fm < 9; ++fm) {
      const int r0 = wm1 * 144 + fm * 16 + quad * 4;
#pragma unroll
      for (int fn = 0; fn < 2; ++fn) {
        const int n = wn1 * 32 + fn * 16 + l15;
        union { __hip_bfloat16 hh[4]; uint2 u; } pk;
#pragma unroll
        for (int ii = 0; ii < 4; ++ii) {
          float v = acc1[fm][fn][ii];
          v = (r0 + ii < 266) ? (fmaxf(v, 0.f) + EPS_F) : 0.f;
          pk.hh[ii] = (__hip_bfloat16)v;
        }
        *(uint2*)(QP + n * 592 + r0 * 2) = pk.u;
      }
    }
    asm volatile("s_waitcnt lgkmcnt(0)" ::: "memory");
    __builtin_amdgcn_s_barrier();  // qp visible
    asm volatile("" ::: "memory");
    // GEMM2: out(128x80) = qp . kvxb^T  (K=288)
    f32x4 acc2[5] = {};
#pragma unroll
    for (int ks = 0; ks < 9; ++ks) {
      const int cb = ks * 64 + quad * 16;
      const bf16x8 af = *(const bf16x8*)(QP + (wave * 16 + l15) * 592 + cb);
      bf16x8 bfr[5];
#pragma unroll
      for (int fd = 0; fd < 5; ++fd)
        bfr[fd] = *(const bf16x8*)(KX + (fd * 16 + l15) * 592 + cb);
#pragma unroll
      for (int fd = 0; fd < 5; ++fd)
        acc2[fd] = __builtin_amdgcn_mfma_f32_16x16x32_bf16(af, bfr[fd],
                                                           acc2[fd], 0, 0, 0);
    }
    if (l15 == 0) {
#pragma unroll
      for (int ii = 0; ii < 4; ++ii)
        Dsh[wave * 16 + quad * 4 + ii] = acc2[4][ii];
    }
    asm volatile("s_waitcnt lgkmcnt(0)" ::: "memory");
    __builtin_amdgcn_s_barrier();  // Dsh visible; all qp reads consumed
    asm volatile("" ::: "memory");
#pragma unroll
    for (int ii = 0; ii < 4; ++ii) {
      const int nloc = wave * 16 + quad * 4 + ii;
      const float den = Dsh[nloc];
      const float dinv = (den > 1e-30f) ? (1.f / den) : 0.f;
      __hip_bfloat16* rowp =
          outm + (rowbase + (long)s * 128 + nloc) * 1024 + h * 64;
#pragma unroll
      for (int fd = 0; fd < 4; ++fd)
        rowp[fd * 16 + l15] = (__hip_bfloat16)(acc2[fd][ii] * dinv);
    }
  }
}

// xb = bf16(x), 8 elements/thread
__global__ void cvt_x(const float* __restrict__ x,
                      __hip_bfloat16* __restrict__ xb) {
  const long i = ((long)blockIdx.x * 256 + threadIdx.x) * 8;
  const float4 f0 = *(const float4*)(x + i);
  const float4 f1 = *(const float4*)(x + i + 4);
  union { __hip_bfloat16 h[8]; uint4 u; } r;
  r.h[0] = (__hip_bfloat16)f0.x; r.h[1] = (__hip_bfloat16)f0.y;
  r.h[2] = (__hip_bfloat16)f0.z; r.h[3] = (__hip_bfloat16)f0.w;
  r.h[4] = (__hip_bfloat16)f1.x; r.h[5] = (__hip_bfloat16)f1.y;
  r.h[6] = (__hip_bfloat16)f1.z; r.h[7] = (__hip_bfloat16)f1.w;
  *(uint4*)(xb + i) = r.u;
}

// all 4 weight transposes in one launch: z in 0..3 picks src/dst.
__global__ void transpose_w4(const float* __restrict__ s0,
                             const float* __restrict__ s1,
                             const float* __restrict__ s2,
                             const float* __restrict__ s3,
                             __hip_bfloat16* __restrict__ dq,
                             __hip_bfloat16* __restrict__ dwo) {
  __shared__ float t[32][33];
  const int z = blockIdx.z;
  const float* src = (z == 0) ? s0 : (z == 1) ? s1 : (z == 2) ? s2 : s3;
  __hip_bfloat16* dst = (z < 3) ? (dq + (long)z * 1048576) : dwo;
  const int k0 = blockIdx.x * 32, n0 = blockIdx.y * 32;
  const int tx = threadIdx.x & 31, ty = threadIdx.x >> 5;
#pragma unroll
  for (int i = 0; i < 4; ++i)
    t[ty + i * 8][tx] = src[(long)(k0 + ty + i * 8) * 1024 + n0 + tx];
  __syncthreads();
#pragma unroll
  for (int i = 0; i < 4; ++i)
    dst[(long)(n0 + ty + i * 8) * 1024 + k0 + tx] =
        (__hip_bfloat16)t[tx][ty + i * 8];
}

// projb (288x64 bf16): rows<266 = bf16(proj), rows 266..287 exact zero.
__global__ void prep_proj(const float* __restrict__ proj,
                          __hip_bfloat16* __restrict__ projb) {
  const int i = blockIdx.x * 256 + threadIdx.x;
  if (i < 288 * 64) {
    const int r = i >> 6;
    __hip_bfloat16 v = (__hip_bfloat16)0.f;
    if (r < 266) v = (__hip_bfloat16)proj[i];
    projb[i] = v;
  }
}

// ---------------------------------------------------------------------------
extern "C" void kernel_launch(void* const* d_in, const int* in_sizes, int n_in,
                              void* d_out, int out_size, void* d_ws,
                              size_t ws_size, hipStream_t stream) {
  const float* x    = (const float*)d_in[0];
  const float* Wq   = (const float*)d_in[1];
  const float* Wk   = (const float*)d_in[2];
  const float* Wv   = (const float*)d_in[3];
  const float* Wo   = (const float*)d_in[4];
  const float* bo   = (const float*)d_in[5];
  const float* proj = (const float*)d_in[6];
  float* out = (float*)d_out;
  char* ws = (char*)d_ws;

  // ws layout (bytes); total 135,630,848 (proven fit)
  constexpr long o_wqkvt = 0;            // 6,291,456
  constexpr long o_wot   = 6291456;      // 2,097,152
  constexpr long o_projb = 8388608;      // 36,864
  constexpr long o_Qb    = 8425472;      // 33,554,432
  constexpr long o_Kb    = 41979904;     // 33,554,432 (alias outm)
  constexpr long o_Vb    = 75534336;     // 33,554,432
  constexpr long o_xb    = 109088768;    // 33,554,432 (alias kvp/kvxb)
  constexpr long o_kvp   = 109088768;    // 4*64*23040*4 = 23,592,960
  constexpr long o_kvxb  = 132681728;    // 64*23040*2   =  2,949,120

  __hip_bfloat16* wqkvt = (__hip_bfloat16*)(ws + o_wqkvt);
  __hip_bfloat16* wot   = (__hip_bfloat16*)(ws + o_wot);
  __hip_bfloat16* projb = (__hip_bfloat16*)(ws + o_projb);
  __hip_bfloat16* Qb    = (__hip_bfloat16*)(ws + o_Qb);
  __hip_bfloat16* Kb    = (__hip_bfloat16*)(ws + o_Kb);
  __hip_bfloat16* Vb    = (__hip_bfloat16*)(ws + o_Vb);
  __hip_bfloat16* xb    = (__hip_bfloat16*)(ws + o_xb);
  float*          kvp   = (float*)(ws + o_kvp);
  __hip_bfloat16* kvxb  = (__hip_bfloat16*)(ws + o_kvxb);
  __hip_bfloat16* outm  = Kb;  // alias: Kb dead after favor_kv

  // prep
  cvt_x<<<8192, 256, 0, stream>>>(x, xb);
  transpose_w4<<<dim3(32, 32, 4), 256, 0, stream>>>(Wq, Wk, Wv, Wo, wqkvt,
                                                    wot);
  prep_proj<<<72, 256, 0, stream>>>(proj, projb);

  // S1 fused: [Qb|Kb|Vb] = xb . wqkvt^T  (256^2 pipeline GEMM, EPI7)
  gemm256<7><<<768, 512, 0, stream>>>(xb, 1024, wqkvt, 1024, Qb, 0, 64, 12,
                                      1024, nullptr);

  // phase A fused: kvp partials, then reduce+transpose to kvxb
  favor_kv<<<256, 512, 0, stream>>>(Kb, Vb, projb, kvp);
  finalize_kvx2<<<64, 256, 0, stream>>>(kvp, kvxb);

  // phase B fused: outm = (relu(Q.projb^T)+eps) . kvxb^T / denom, merged
  favor_out<<<512, 512, 0, stream>>>(Qb, kvxb, projb, outm);

  // S5: out(f32) = outm . wot^T + bo  (256^2 pipeline GEMM, EPI5)
  gemm256<5><<<256, 512, 0, stream>>>(outm, 1024, wot, 1024, out, 1024, 64, 4,
                                      1024, bo);
}

// Round 5
// 387.055 us; speedup vs baseline: 2.1602x; 1.0010x over previous
//
#include <hip/hip_runtime.h>
#include <hip/hip_bf16.h>

// ---------------------------------------------------------------------------
// Performer (FAVOR+) attention, MI355X gfx950.  f32 I/O, bf16 MFMA internals.
// R12 == R11 resubmitted after infra failure (container failed; no counters).
// R11: gemm256 K-loop restructured to the 8-phase template (4 phases per
// K-tile, 2 barriers/phase, per-phase {small ds-read batch | stage-issue |
// 16 MFMA}), with sub-tile LDS buffer recycling: tile t+2's quarters are
// staged into buf p as soon as the phase-end barrier proves their last
// reader finished.  vmcnt(8) once per K-tile (counted, never 0 mid-loop).
// LDS layout / swizzle / fragment addressing / XCD-local mapping unchanged
// from the R10-verified kernel.  Favor kernels unchanged from R10.
//   prep:  wqkvt(3072x1024)=bf16([Wq|Wk|Wv]^T); wot=bf16(Wo^T); projb padded
//   S1:    [Qb|Kb|Vb](16384x1024 bf16 each) = xb . wqkvt^T   (gemm256 EPI7)
//   favor_kv (grid 64bh x 4slab): kvxT(288x80) += kp . [V;1]^T per 128 rows
//   finalize_kvx2: kvxb[bh][80][288] bf16 = transpose(sum_slab kvp)
//   favor_out (grid 64bh x 8): qp = relu(Q.projb^T)+eps; out = qp.kvxb^T
//       /denom(col 64); merged-head bf16 store
//   S5:    out(f32) = outm . wot^T + bo (gemm256 EPI5)
// Aliases: xb==kvp/kvxb region (dead after S1); outm==Kb (dead after A).
// ---------------------------------------------------------------------------

typedef __bf16 bf16x8 __attribute__((ext_vector_type(8)));
typedef unsigned short u16x8 __attribute__((ext_vector_type(8)));
typedef float  f32x4  __attribute__((ext_vector_type(4)));

#define EPS_F 1e-3f

__device__ __forceinline__ void gld16(const void* g, void* l) {
  __builtin_amdgcn_global_load_lds(
      (const __attribute__((address_space(1))) void*)g,
      (__attribute__((address_space(3))) void*)l, 16, 0, 0);
}

// ---------------------------------------------------------------------------
// gemm256: 256x256 tile, BK=64, 8 waves (2M x 4N), per-wave 128x64 output.
// 4 phases per K-tile; quadrant order Q1(m0n0) Q2(m0n1) Q3(m1n1) Q4(m1n0).
// Region-free schedule for staging tile t+2 into buf p:
//   after P1: A-quarters {0,2} free (af0 readers done), B free after P2.
//   P2 stages A0,A2 ; P3 stages B0,B1,B2 ; P4 stages B3,A1,A3.
// Requires M%256==0, N%256==0, K%64==0 (K>=128), Mtiles%8==0, Ntiles%4==0.
// ---------------------------------------------------------------------------
template <int EPI>
__global__ void __launch_bounds__(512, 2)
gemm256(const __hip_bfloat16* __restrict__ A, long lda,
        const __hip_bfloat16* __restrict__ Bt, long ldb,
        void* __restrict__ Cp, long ldc,
        int Mtiles, int Ntiles, int K, const float* __restrict__ bias) {
  __shared__ __align__(16) char sm[131072];

  const int tid  = threadIdx.x;
  const int lane = tid & 63;
  const int wave = tid >> 6;   // 0..7
  const int wm   = wave >> 2;  // 0..1
  const int wn   = wave & 3;   // 0..3
  const int quad = lane >> 4;
  const int l15  = lane & 15;

  // XCD-local mapping (R10-verified): XCD x owns mt in [x*Mx,(x+1)*Mx);
  // walks 4-nt groups of Mx*4 blocks -> live set A 4MB + B 2MB ~ one L2.
  const int bid = blockIdx.x;
  const int Mx  = Mtiles >> 3;
  const int xcd = bid & 7;
  const int wl  = bid >> 3;
  const int gsz = Mx << 2;
  const int grp = wl / gsz;
  const int rr  = wl - grp * gsz;
  const int mt  = xcd * Mx + (rr % Mx);
  const int nt  = (grp << 2) + (rr / Mx);
  const long m0 = (long)mt * 256;
  const long n0 = (long)nt * 256;

  const int srow = tid >> 3;
  const int sg   = (tid & 7) ^ (srow & 7);
  const __hip_bfloat16* aS = A  + (m0 + srow) * lda + sg * 8;
  const __hip_bfloat16* bS = Bt + (n0 + srow) * ldb + sg * 8;
  char* smc = (char*)sm;
  const int ldsOff = tid * 16;

  const int aRowB = (wm * 128 + l15) * 128;
  const int bRowB = 32768 + (wn * 64 + l15) * 128;
  const int sw    = (l15 & 7) << 4;
  const int cx0   = (quad * 16) ^ sw;
  const int cx1   = (64 + quad * 16) ^ sw;

  f32x4 acc[8][4] = {};

#define GLD_A(pp, kk, i)                                                   \
  gld16(aS + (long)(i) * 64 * lda + (kk),                                  \
        smc + (pp) * 65536 + (i) * 8192 + ldsOff);
#define GLD_B(pp, kk, i)                                                   \
  gld16(bS + (long)(i) * 64 * ldb + (kk),                                  \
        smc + (pp) * 65536 + 32768 + (i) * 8192 + ldsOff);

  const int NT = K >> 6;
  // prologue: stage tiles 0 (buf0) and 1 (buf1) fully
#pragma unroll
  for (int i = 0; i < 4; ++i) { GLD_A(0, 0, i) GLD_B(0, 0, i) }
#pragma unroll
  for (int i = 0; i < 4; ++i) { GLD_A(1, 64, i) GLD_B(1, 64, i) }
  asm volatile("s_waitcnt vmcnt(8)" ::: "memory");  // tile 0 resident
  __builtin_amdgcn_s_barrier();
  asm volatile("" ::: "memory");

  int p = 0;
  for (int t = 0; t < NT; ++t) {
    const char* base = smc + p * 65536;
    const long kk = (long)(t + 2) * 64;
    const bool pf = (t + 2 < NT);
    bf16x8 af[4][2], b01[2][2], b23[2][2];

    // ---- P1: read af0 (8) + b01 (4); MFMA Q1 = m0 x n0
#pragma unroll
    for (int it = 0; it < 4; ++it) {
      af[it][0] = *(const bf16x8*)(base + aRowB + it * 2048 + cx0);
      af[it][1] = *(const bf16x8*)(base + aRowB + it * 2048 + cx1);
    }
#pragma unroll
    for (int jt = 0; jt < 2; ++jt) {
      b01[jt][0] = *(const bf16x8*)(base + bRowB + jt * 2048 + cx0);
      b01[jt][1] = *(const bf16x8*)(base + bRowB + jt * 2048 + cx1);
    }
    asm volatile("" ::: "memory");
    __builtin_amdgcn_s_barrier();
    asm volatile("s_waitcnt lgkmcnt(0)" ::: "memory");
    __builtin_amdgcn_s_setprio(1);
#pragma unroll
    for (int it = 0; it < 4; ++it)
#pragma unroll
      for (int jt = 0; jt < 2; ++jt) {
        acc[it][jt] = __builtin_amdgcn_mfma_f32_16x16x32_bf16(
            af[it][0], b01[jt][0], acc[it][jt], 0, 0, 0);
        acc[it][jt] = __builtin_amdgcn_mfma_f32_16x16x32_bf16(
            af[it][1], b01[jt][1], acc[it][jt], 0, 0, 0);
      }
    __builtin_amdgcn_s_setprio(0);
    __builtin_amdgcn_s_barrier();
    asm volatile("" ::: "memory");

    // ---- P2: read b23 (4); stage A0,A2 (freed by P1); MFMA Q2 = m0 x n1
#pragma unroll
    for (int jt = 0; jt < 2; ++jt) {
      b23[jt][0] = *(const bf16x8*)(base + bRowB + (jt + 2) * 2048 + cx0);
      b23[jt][1] = *(const bf16x8*)(base + bRowB + (jt + 2) * 2048 + cx1);
    }
    if (pf) { GLD_A(p, kk, 0) GLD_A(p, kk, 2) }
    asm volatile("" ::: "memory");
    __builtin_amdgcn_s_barrier();
    asm volatile("s_waitcnt lgkmcnt(0)" ::: "memory");
    __builtin_amdgcn_s_setprio(1);
#pragma unroll
    for (int it = 0; it < 4; ++it)
#pragma unroll
      for (int jt = 0; jt < 2; ++jt) {
        acc[it][jt + 2] = __builtin_amdgcn_mfma_f32_16x16x32_bf16(
            af[it][0], b23[jt][0], acc[it][jt + 2], 0, 0, 0);
        acc[it][jt + 2] = __builtin_amdgcn_mfma_f32_16x16x32_bf16(
            af[it][1], b23[jt][1], acc[it][jt + 2], 0, 0, 0);
      }
    __builtin_amdgcn_s_setprio(0);
    __builtin_amdgcn_s_barrier();
    asm volatile("" ::: "memory");

    // ---- P3: read af1 (8); stage B0,B1,B2 (freed by P2); MFMA Q3 = m1 x n1
#pragma unroll
    for (int it = 0; it < 4; ++it) {
      af[it][0] = *(const bf16x8*)(base + aRowB + (4 + it) * 2048 + cx0);
      af[it][1] = *(const bf16x8*)(base + aRowB + (4 + it) * 2048 + cx1);
    }
    if (pf) { GLD_B(p, kk, 0) GLD_B(p, kk, 1) GLD_B(p, kk, 2) }
    asm volatile("" ::: "memory");
    __builtin_amdgcn_s_barrier();
    asm volatile("s_waitcnt lgkmcnt(0)" ::: "memory");
    __builtin_amdgcn_s_setprio(1);
#pragma unroll
    for (int it = 0; it < 4; ++it)
#pragma unroll
      for (int jt = 0; jt < 2; ++jt) {
        acc[4 + it][jt + 2] = __builtin_amdgcn_mfma_f32_16x16x32_bf16(
            af[it][0], b23[jt][0], acc[4 + it][jt + 2], 0, 0, 0);
        acc[4 + it][jt + 2] = __builtin_amdgcn_mfma_f32_16x16x32_bf16(
            af[it][1], b23[jt][1], acc[4 + it][jt + 2], 0, 0, 0);
      }
    __builtin_amdgcn_s_setprio(0);
    __builtin_amdgcn_s_barrier();
    asm volatile("" ::: "memory");

    // ---- P4: no reads (b01 kept in regs); stage B3,A1,A3 (freed by P3);
    //          MFMA Q4 = m1 x n0; counted vmcnt once per K-tile.
    if (pf) { GLD_B(p, kk, 3) GLD_A(p, kk, 1) GLD_A(p, kk, 3) }
    asm volatile("" ::: "memory");
    __builtin_amdgcn_s_barrier();
    __builtin_amdgcn_s_setprio(1);
#pragma unroll
    for (int it = 0; it < 4; ++it)
#pragma unroll
      for (int jt = 0; jt < 2; ++jt) {
        acc[4 + it][jt] = __builtin_amdgcn_mfma_f32_16x16x32_bf16(
            af[it][0], b01[jt][0], acc[4 + it][jt], 0, 0, 0);
        acc[4 + it][jt] = __builtin_amdgcn_mfma_f32_16x16x32_bf16(
            af[it][1], b01[jt][1], acc[4 + it][jt], 0, 0, 0);
      }
    __builtin_amdgcn_s_setprio(0);
    if (pf) {
      asm volatile("s_waitcnt vmcnt(8)" ::: "memory");  // tile t+1 resident
    } else {
      asm volatile("s_waitcnt vmcnt(0)" ::: "memory");  // tail drain
    }
    __builtin_amdgcn_s_barrier();
    asm volatile("" ::: "memory");
    p ^= 1;
  }
#undef GLD_A
#undef GLD_B

  if constexpr (EPI == 7) {
    __hip_bfloat16* Cb = (__hip_bfloat16*)Cp;
    const long slab  = (n0 >> 10) * 16777216;
    const long ncol0 = (n0 & 1023) + wn * 64 + l15;
#pragma unroll
    for (int it = 0; it < 8; ++it) {
#pragma unroll
      for (int i = 0; i < 4; ++i) {
        const long gm = m0 + wm * 128 + it * 16 + quad * 4 + i;
        __hip_bfloat16* rowp = Cb + slab + gm * 1024 + ncol0;
#pragma unroll
        for (int jt = 0; jt < 4; ++jt)
          rowp[jt * 16] = (__hip_bfloat16)acc[it][jt][i];
      }
    }
  } else if constexpr (EPI == 5) {
    float* Cf = (float*)Cp;
    float bv[4];
#pragma unroll
    for (int jt = 0; jt < 4; ++jt)
      bv[jt] = bias[n0 + wn * 64 + jt * 16 + l15];
#pragma unroll
    for (int it = 0; it < 8; ++it) {
#pragma unroll
      for (int i = 0; i < 4; ++i) {
        const long gm = m0 + wm * 128 + it * 16 + quad * 4 + i;
        float* rowp = Cf + gm * ldc + n0 + wn * 64 + l15;
#pragma unroll
        for (int jt = 0; jt < 4; ++jt)
          rowp[jt * 16] = acc[it][jt][i] + bv[jt];
      }
    }
  }
}

// ---------------------------------------------------------------------------
// favor_kv: fused kp = relu(projb.K^T)+eps ; kvxT(288x80) += kp . [V;1]^T
// (unchanged from R10-verified)
// ---------------------------------------------------------------------------
__global__ void __launch_bounds__(512, 2)
favor_kv(const __hip_bfloat16* __restrict__ Kb,
         const __hip_bfloat16* __restrict__ Vb,
         const __hip_bfloat16* __restrict__ projb_g,
         float* __restrict__ kvp) {
  __shared__ __align__(16) char sm[147456];
  char* Kt = sm;
  char* Pj = sm + 16384;
  char* KP = sm + 53248;
  char* VT = sm + 126976;

  const int tid  = threadIdx.x;
  const int lane = tid & 63;
  const int wave = tid >> 6;
  const int quad = lane >> 4;
  const int l15  = lane & 15;
  const int swL  = (l15 & 7) << 4;

  const int bh   = blockIdx.x & 63;
  const int slab = blockIdx.x >> 6;  // 0..3
  const int b    = bh >> 4, h = bh & 15;
  const long rowbase = (long)b * 4096 + (long)slab * 1024;

  for (int p = 0; p < 5; ++p) {
    const int idx = p * 512 + tid;
    if (idx < 2304) {
      const int r = idx >> 3, g = (idx & 7) ^ (r & 7);
      gld16(projb_g + r * 64 + g * 8, Pj + p * 8192 + tid * 16);
    }
  }
  {
    unsigned short* vth = (unsigned short*)(VT + 64 * 256);
    const unsigned short one_bf = 0x3F80;
    for (int i = tid; i < 2048; i += 512) vth[i] = (i < 128) ? one_bf : 0;
  }

  const int rS = tid >> 3, gS = (tid & 7) ^ (rS & 7);
  const int rS2 = rS + 64, gS2 = (tid & 7) ^ (rS2 & 7);
  const int nl = tid >> 3, seg = tid & 7;
  gld16(Kb + (rowbase + rS) * 1024 + h * 64 + gS * 8, Kt + tid * 16);
  gld16(Kb + (rowbase + rS2) * 1024 + h * 64 + gS2 * 8, Kt + 8192 + tid * 16);
  u16x8 vc0 = *(const u16x8*)(Vb + (rowbase + nl) * 1024 + h * 64 + seg * 8);
  u16x8 vc1 =
      *(const u16x8*)(Vb + (rowbase + 64 + nl) * 1024 + h * 64 + seg * 8);

  const int wm1 = wave & 3;
  const int wn1 = wave >> 2;
  const int nJ = (wave < 2) ? 3 : 2;

  f32x4 acc2[3][5] = {};

  for (int t = 0; t < 8; ++t) {
    asm volatile("s_waitcnt vmcnt(0)" ::: "memory");
    __builtin_amdgcn_s_barrier();
    asm volatile("" ::: "memory");
    {
#pragma unroll
      for (int j = 0; j < 8; ++j) {
        const int d = seg * 8 + j;
        const int s = ((d & 7) ^ ((d >> 3) & 7)) << 4;
        *(unsigned short*)(VT + d * 256 + ((nl * 2) ^ s)) = vc0[j];
        *(unsigned short*)(VT + d * 256 + (((nl + 64) * 2) ^ s)) = vc1[j];
      }
    }
    f32x4 acc1[2][9] = {};
#pragma unroll
    for (int ks = 0; ks < 2; ++ks) {
      const int cb = ks * 64 + quad * 16;
      bf16x8 af[2];
#pragma unroll
      for (int fm = 0; fm < 2; ++fm)
        af[fm] = *(const bf16x8*)(Kt + (wm1 * 32 + fm * 16 + l15) * 128 +
                                  (cb ^ swL));
      bf16x8 bfr[9];
#pragma unroll
      for (int fn = 0; fn < 9; ++fn)
        bfr[fn] = *(const bf16x8*)(Pj + (wn1 * 144 + fn * 16 + l15) * 128 +
                                   (cb ^ swL));
#pragma unroll
      for (int fm = 0; fm < 2; ++fm)
#pragma unroll
        for (int fn = 0; fn < 9; ++fn)
          acc1[fm][fn] = __builtin_amdgcn_mfma_f32_16x16x32_bf16(
              af[fm], bfr[fn], acc1[fm][fn], 0, 0, 0);
    }
#pragma unroll
    for (int fm = 0; fm < 2; ++fm) {
      const int nb = (wm1 * 32 + fm * 16 + quad * 4) * 2;
#pragma unroll
      for (int fn = 0; fn < 9; ++fn) {
        const int r = wn1 * 144 + fn * 16 + l15;
        const bool ok = (r < 266);
        union { __hip_bfloat16 hh[4]; uint2 u; } pk;
#pragma unroll
        for (int ii = 0; ii < 4; ++ii) {
          float v = acc1[fm][fn][ii];
          v = ok ? (fmaxf(v, 0.f) + EPS_F) : 0.f;
          pk.hh[ii] = (__hip_bfloat16)v;
        }
        *(uint2*)(KP + r * 256 + (nb ^ ((r & 7) << 4))) = pk.u;
      }
    }
    asm volatile("s_waitcnt lgkmcnt(0)" ::: "memory");
    __builtin_amdgcn_s_barrier();
    asm volatile("" ::: "memory");
    if (t < 7) {
      const long n1 = (long)(t + 1) * 128;
      gld16(Kb + (rowbase + n1 + rS) * 1024 + h * 64 + gS * 8, Kt + tid * 16);
      gld16(Kb + (rowbase + n1 + rS2) * 1024 + h * 64 + gS2 * 8,
            Kt + 8192 + tid * 16);
      vc0 = *(const u16x8*)(Vb + (rowbase + n1 + nl) * 1024 + h * 64 +
                            seg * 8);
      vc1 = *(const u16x8*)(Vb + (rowbase + n1 + 64 + nl) * 1024 + h * 64 +
                            seg * 8);
    }
#pragma unroll
    for (int ks = 0; ks < 4; ++ks) {
      const int cb = ks * 64 + quad * 16;
      bf16x8 bfr[5];
#pragma unroll
      for (int fd = 0; fd < 5; ++fd) {
        const int d = fd * 16 + l15;
        const int s = ((d & 7) ^ ((d >> 3) & 7)) << 4;
        bfr[fd] = *(const bf16x8*)(VT + d * 256 + (cb ^ s));
      }
#pragma unroll
      for (int j = 0; j < 3; ++j) {
        if (j < nJ) {
          const int r = (wave + 8 * j) * 16 + l15;
          const bf16x8 af =
              *(const bf16x8*)(KP + r * 256 + (cb ^ ((r & 7) << 4)));
#pragma unroll
          for (int fd = 0; fd < 5; ++fd)
            acc2[j][fd] = __builtin_amdgcn_mfma_f32_16x16x32_bf16(
                af, bfr[fd], acc2[j][fd], 0, 0, 0);
        }
      }
    }
  }
  float* dst = kvp + (long)blockIdx.x * 23040;
#pragma unroll
  for (int j = 0; j < 3; ++j) {
    if (j < nJ) {
      const int rb = (wave + 8 * j) * 16 + quad * 4;
#pragma unroll
      for (int fd = 0; fd < 5; ++fd) {
        const int d = fd * 16 + l15;
#pragma unroll
        for (int ii = 0; ii < 4; ++ii)
          dst[(long)(rb + ii) * 80 + d] = acc2[j][fd][ii];
      }
    }
  }
}

// kvxb[bh][d][r] bf16 = sum_slab kvp[slab][bh][r][d]
__global__ void __launch_bounds__(256)
finalize_kvx2(const float* __restrict__ kvp,
              __hip_bfloat16* __restrict__ kvxb) {
  __shared__ float lds_f[23040];
  const int bh = blockIdx.x, t = threadIdx.x;
  for (int p = 0; p < 90; ++p) {
    const int idx = p * 256 + t;
    float s = 0.f;
#pragma unroll
    for (int sl = 0; sl < 4; ++sl)
      s += kvp[(long)(sl * 64 + bh) * 23040 + idx];
    lds_f[idx] = s;
  }
  __syncthreads();
  for (int p = 0; p < 90; ++p) {
    const int idx = p * 256 + t;
    const int d = idx / 288, r = idx % 288;
    kvxb[(long)bh * 23040 + idx] = (__hip_bfloat16)lds_f[r * 80 + d];
  }
}

// ---------------------------------------------------------------------------
// favor_out: qp = relu(Q.projb^T)+eps ; out = (qp . kvxb^T)/denom, merged
// (unchanged from R10-verified)
// ---------------------------------------------------------------------------
__global__ void __launch_bounds__(512, 2)
favor_out(const __hip_bfloat16* __restrict__ Qb,
          const __hip_bfloat16* __restrict__ kvxb_g,
          const __hip_bfloat16* __restrict__ projb_g,
          __hip_bfloat16* __restrict__ outm) {
  __shared__ __align__(16) char sm[160512];
  char* Pj = sm;
  char* KX = sm + 36864;
  char* QP = sm + 84224;
  float* Dsh = (float*)(sm + 160000);

  const int tid  = threadIdx.x;
  const int lane = tid & 63;
  const int wave = tid >> 6;
  const int quad = lane >> 4;
  const int l15  = lane & 15;
  const int swL  = (l15 & 7) << 4;

  const int bh  = blockIdx.x >> 3;
  const int rb8 = blockIdx.x & 7;
  const int b = bh >> 4, h = bh & 15;
  const long rowbase = (long)b * 4096 + (long)rb8 * 512;

  for (int p = 0; p < 5; ++p) {
    const int idx = p * 512 + tid;
    if (idx < 2304) {
      const int r = idx >> 3, g = (idx & 7) ^ (r & 7);
      gld16(projb_g + r * 64 + g * 8, Pj + p * 8192 + tid * 16);
    }
  }
  {
    const __hip_bfloat16* src = kvxb_g + (long)bh * 23040;
#pragma unroll
    for (int p = 0; p < 6; ++p) {
      const int idx = p * 512 + tid;
      if (idx < 2880) {
        const int d = idx / 36, g = idx % 36;
        const bf16x8 v = *(const bf16x8*)(src + d * 288 + g * 8);
        *(bf16x8*)(KX + d * 592 + g * 16) = v;
      }
    }
  }
  const int rS = tid >> 3, gS = (tid & 7) ^ (rS & 7);
  const int rS2 = rS + 64, gS2 = (tid & 7) ^ (rS2 & 7);
  u16x8 qv0 = *(const u16x8*)(Qb + (rowbase + rS) * 1024 + h * 64 + gS * 8);
  u16x8 qv1 = *(const u16x8*)(Qb + (rowbase + rS2) * 1024 + h * 64 + gS2 * 8);

  const int wm1 = wave >> 2;
  const int wn1 = wave & 3;

  for (int s = 0; s < 4; ++s) {
    *(u16x8*)(QP + tid * 16) = qv0;
    *(u16x8*)(QP + 8192 + tid * 16) = qv1;
    asm volatile("s_waitcnt lgkmcnt(0)" ::: "memory");
    if (s == 0) asm volatile("s_waitcnt vmcnt(0)" ::: "memory");
    __builtin_amdgcn_s_barrier();
    asm volatile("" ::: "memory");
    f32x4 acc1[9][2] = {};
#pragma unroll
    for (int ks = 0; ks < 2; ++ks) {
      const int cb = ks * 64 + quad * 16;
      bf16x8 bfr[2];
#pragma unroll
      for (int fn = 0; fn < 2; ++fn)
        bfr[fn] = *(const bf16x8*)(QP + (wn1 * 32 + fn * 16 + l15) * 128 +
                                   (cb ^ swL));
      bf16x8 af[9];
#pragma unroll
      for (int fm = 0; fm < 9; ++fm)
        af[fm] = *(const bf16x8*)(Pj + (wm1 * 144 + fm * 16 + l15) * 128 +
                                  (cb ^ swL));
#pragma unroll
      for (int fm = 0; fm < 9; ++fm)
#pragma unroll
        for (int fn = 0; fn < 2; ++fn)
          acc1[fm][fn] = __builtin_amdgcn_mfma_f32_16x16x32_bf16(
              af[fm], bfr[fn], acc1[fm][fn], 0, 0, 0);
    }
    if (s < 3) {
      const long n1 = (long)(s + 1) * 128;
      qv0 = *(const u16x8*)(Qb + (rowbase + n1 + rS) * 1024 + h * 64 + gS * 8);
      qv1 = *(const u16x8*)(Qb + (rowbase + n1 + rS2) * 1024 + h * 64 +
                            gS2 * 8);
    }
    __builtin_amdgcn_s_barrier();
    asm volatile("" ::: "memory");
#pragma unroll
    for (int fm = 0; fm < 9; ++fm) {
      const int r0 = wm1 * 144 + fm * 16 + quad * 4;
#pragma unroll
      for (int fn = 0; fn < 2; ++fn) {
        const int n = wn1 * 32 + fn * 16 + l15;
        union { __hip_bfloat16 hh[4]; uint2 u; } pk;
#pragma unroll
        for (int ii = 0; ii < 4; ++ii) {
          float v = acc1[fm][fn][ii];
          v = (r0 + ii < 266) ? (fmaxf(v, 0.f) + EPS_F) : 0.f;
          pk.hh[ii] = (__hip_bfloat16)v;
        }
        *(uint2*)(QP + n * 592 + r0 * 2) = pk.u;
      }
    }
    asm volatile("s_waitcnt lgkmcnt(0)" ::: "memory");
    __builtin_amdgcn_s_barrier();
    asm volatile("" ::: "memory");
    f32x4 acc2[5] = {};
#pragma unroll
    for (int ks = 0; ks < 9; ++ks) {
      const int cb = ks * 64 + quad * 16;
      const bf16x8 af = *(const bf16x8*)(QP + (wave * 16 + l15) * 592 + cb);
      bf16x8 bfr[5];
#pragma unroll
      for (int fd = 0; fd < 5; ++fd)
        bfr[fd] = *(const bf16x8*)(KX + (fd * 16 + l15) * 592 + cb);
#pragma unroll
      for (int fd = 0; fd < 5; ++fd)
        acc2[fd] = __builtin_amdgcn_mfma_f32_16x16x32_bf16(af, bfr[fd],
                                                           acc2[fd], 0, 0, 0);
    }
    if (l15 == 0) {
#pragma unroll
      for (int ii = 0; ii < 4; ++ii)
        Dsh[wave * 16 + quad * 4 + ii] = acc2[4][ii];
    }
    asm volatile("s_waitcnt lgkmcnt(0)" ::: "memory");
    __builtin_amdgcn_s_barrier();
    asm volatile("" ::: "memory");
#pragma unroll
    for (int ii = 0; ii < 4; ++ii) {
      const int nloc = wave * 16 + quad * 4 + ii;
      const float den = Dsh[nloc];
      const float dinv = (den > 1e-30f) ? (1.f / den) : 0.f;
      __hip_bfloat16* rowp =
          outm + (rowbase + (long)s * 128 + nloc) * 1024 + h * 64;
#pragma unroll
      for (int fd = 0; fd < 4; ++fd)
        rowp[fd * 16 + l15] = (__hip_bfloat16)(acc2[fd][ii] * dinv);
    }
  }
}

// xb = bf16(x), 8 elements/thread
__global__ void cvt_x(const float* __restrict__ x,
                      __hip_bfloat16* __restrict__ xb) {
  const long i = ((long)blockIdx.x * 256 + threadIdx.x) * 8;
  const float4 f0 = *(const float4*)(x + i);
  const float4 f1 = *(const float4*)(x + i + 4);
  union { __hip_bfloat16 h[8]; uint4 u; } r;
  r.h[0] = (__hip_bfloat16)f0.x; r.h[1] = (__hip_bfloat16)f0.y;
  r.h[2] = (__hip_bfloat16)f0.z; r.h[3] = (__hip_bfloat16)f0.w;
  r.h[4] = (__hip_bfloat16)f1.x; r.h[5] = (__hip_bfloat16)f1.y;
  r.h[6] = (__hip_bfloat16)f1.z; r.h[7] = (__hip_bfloat16)f1.w;
  *(uint4*)(xb + i) = r.u;
}

// all 4 weight transposes in one launch: z in 0..3 picks src/dst.
__global__ void transpose_w4(const float* __restrict__ s0,
                             const float* __restrict__ s1,
                             const float* __restrict__ s2,
                             const float* __restrict__ s3,
                             __hip_bfloat16* __restrict__ dq,
                             __hip_bfloat16* __restrict__ dwo) {
  __shared__ float t[32][33];
  const int z = blockIdx.z;
  const float* src = (z == 0) ? s0 : (z == 1) ? s1 : (z == 2) ? s2 : s3;
  __hip_bfloat16* dst = (z < 3) ? (dq + (long)z * 1048576) : dwo;
  const int k0 = blockIdx.x * 32, n0 = blockIdx.y * 32;
  const int tx = threadIdx.x & 31, ty = threadIdx.x >> 5;
#pragma unroll
  for (int i = 0; i < 4; ++i)
    t[ty + i * 8][tx] = src[(long)(k0 + ty + i * 8) * 1024 + n0 + tx];
  __syncthreads();
#pragma unroll
  for (int i = 0; i < 4; ++i)
    dst[(long)(n0 + ty + i * 8) * 1024 + k0 + tx] =
        (__hip_bfloat16)t[tx][ty + i * 8];
}

// projb (288x64 bf16): rows<266 = bf16(proj), rows 266..287 exact zero.
__global__ void prep_proj(const float* __restrict__ proj,
                          __hip_bfloat16* __restrict__ projb) {
  const int i = blockIdx.x * 256 + threadIdx.x;
  if (i < 288 * 64) {
    const int r = i >> 6;
    __hip_bfloat16 v = (__hip_bfloat16)0.f;
    if (r < 266) v = (__hip_bfloat16)proj[i];
    projb[i] = v;
  }
}

// ---------------------------------------------------------------------------
extern "C" void kernel_launch(void* const* d_in, const int* in_sizes, int n_in,
                              void* d_out, int out_size, void* d_ws,
                              size_t ws_size, hipStream_t stream) {
  const float* x    = (const float*)d_in[0];
  const float* Wq   = (const float*)d_in[1];
  const float* Wk   = (const float*)d_in[2];
  const float* Wv   = (const float*)d_in[3];
  const float* Wo   = (const float*)d_in[4];
  const float* bo   = (const float*)d_in[5];
  const float* proj = (const float*)d_in[6];
  float* out = (float*)d_out;
  char* ws = (char*)d_ws;

  // ws layout (bytes); total 135,630,848 (proven fit)
  constexpr long o_wqkvt = 0;            // 6,291,456
  constexpr long o_wot   = 6291456;      // 2,097,152
  constexpr long o_projb = 8388608;      // 36,864
  constexpr long o_Qb    = 8425472;      // 33,554,432
  constexpr long o_Kb    = 41979904;     // 33,554,432 (alias outm)
  constexpr long o_Vb    = 75534336;     // 33,554,432
  constexpr long o_xb    = 109088768;    // 33,554,432 (alias kvp/kvxb)
  constexpr long o_kvp   = 109088768;    // 4*64*23040*4 = 23,592,960
  constexpr long o_kvxb  = 132681728;    // 64*23040*2   =  2,949,120

  __hip_bfloat16* wqkvt = (__hip_bfloat16*)(ws + o_wqkvt);
  __hip_bfloat16* wot   = (__hip_bfloat16*)(ws + o_wot);
  __hip_bfloat16* projb = (__hip_bfloat16*)(ws + o_projb);
  __hip_bfloat16* Qb    = (__hip_bfloat16*)(ws + o_Qb);
  __hip_bfloat16* Kb    = (__hip_bfloat16*)(ws + o_Kb);
  __hip_bfloat16* Vb    = (__hip_bfloat16*)(ws + o_Vb);
  __hip_bfloat16* xb    = (__hip_bfloat16*)(ws + o_xb);
  float*          kvp   = (float*)(ws + o_kvp);
  __hip_bfloat16* kvxb  = (__hip_bfloat16*)(ws + o_kvxb);
  __hip_bfloat16* outm  = Kb;  // alias: Kb dead after favor_kv

  // prep
  cvt_x<<<8192, 256, 0, stream>>>(x, xb);
  transpose_w4<<<dim3(32, 32, 4), 256, 0, stream>>>(Wq, Wk, Wv, Wo, wqkvt,
                                                    wot);
  prep_proj<<<72, 256, 0, stream>>>(proj, projb);

  // S1 fused: [Qb|Kb|Vb] = xb . wqkvt^T  (256^2 8-phase GEMM, EPI7)
  gemm256<7><<<768, 512, 0, stream>>>(xb, 1024, wqkvt, 1024, Qb, 0, 64, 12,
                                      1024, nullptr);

  // phase A fused: kvp partials, then reduce+transpose to kvxb
  favor_kv<<<256, 512, 0, stream>>>(Kb, Vb, projb, kvp);
  finalize_kvx2<<<64, 256, 0, stream>>>(kvp, kvxb);

  // phase B fused: outm = (relu(Q.projb^T)+eps) . kvxb^T / denom, merged
  favor_out<<<512, 512, 0, stream>>>(Qb, kvxb, projb, outm);

  // S5: out(f32) = outm . wot^T + bo  (256^2 8-phase GEMM, EPI5)
  gemm256<5><<<256, 512, 0, stream>>>(outm, 1024, wot, 1024, out, 1024, 64, 4,
                                      1024, bo);
}

// Round 6
// 380.031 us; speedup vs baseline: 2.2001x; 1.0185x over previous
//
#include <hip/hip_runtime.h>
#include <hip/hip_bf16.h>

// ---------------------------------------------------------------------------
// Performer (FAVOR+) attention, MI355X gfx950.  f32 I/O, bf16 MFMA internals.
// R13: gemm256 K-loop rebuilt as a WITHIN-WAVE read/MFMA pipeline:
//  - K=64 tile split in two 32-halves; 8 clusters of 8 MFMA per tile.
//  - Each cluster's fragment ds_reads are issued BEFORE the previous
//    cluster's MFMAs with NO waitcnt between (compiler inserts counted
//    lgkmcnt on the true deps) -> LDS pipe runs under the matrix pipe
//    instead of alternating with it (the 36%-MfmaUtil ceiling of R8-R12).
//  - Only 2 barriers per K-tile: lgkmcnt(0)+barrier before staging buf p,
//    vmcnt(8)+barrier before next-tile reads (counted, never 0 mid-loop).
//  - Per-acc-entry accumulation order unchanged (cx0 then cx1) ->
//    bit-identical results.  LDS layout/swizzle/XCD mapping = R10-verified.
// Favor kernels and all prep unchanged from R12 (verified).
//   prep:  wqkvt(3072x1024)=bf16([Wq|Wk|Wv]^T); wot=bf16(Wo^T); projb padded
//   S1:    [Qb|Kb|Vb](16384x1024 bf16 each) = xb . wqkvt^T   (gemm256 EPI7)
//   favor_kv (grid 64bh x 4slab): kvxT(288x80) += kp . [V;1]^T per 128 rows
//   finalize_kvx2: kvxb[bh][80][288] bf16 = transpose(sum_slab kvp)
//   favor_out (grid 64bh x 8): qp = relu(Q.projb^T)+eps; out = qp.kvxb^T
//       /denom(col 64); merged-head bf16 store
//   S5:    out(f32) = outm . wot^T + bo (gemm256 EPI5)
// Aliases: xb==kvp/kvxb region (dead after S1); outm==Kb (dead after A).
// ---------------------------------------------------------------------------

typedef __bf16 bf16x8 __attribute__((ext_vector_type(8)));
typedef unsigned short u16x8 __attribute__((ext_vector_type(8)));
typedef float  f32x4  __attribute__((ext_vector_type(4)));

#define EPS_F 1e-3f

__device__ __forceinline__ void gld16(const void* g, void* l) {
  __builtin_amdgcn_global_load_lds(
      (const __attribute__((address_space(1))) void*)g,
      (__attribute__((address_space(3))) void*)l, 16, 0, 0);
}

// ---------------------------------------------------------------------------
// gemm256: 256x256 tile, BK=64, 8 waves (2M x 4N), per-wave 128x64 output.
// Requires M%256==0, N%256==0, K%64==0 (K>=128), Mtiles%8==0, Ntiles%4==0.
// ---------------------------------------------------------------------------
template <int EPI>
__global__ void __launch_bounds__(512, 2)
gemm256(const __hip_bfloat16* __restrict__ A, long lda,
        const __hip_bfloat16* __restrict__ Bt, long ldb,
        void* __restrict__ Cp, long ldc,
        int Mtiles, int Ntiles, int K, const float* __restrict__ bias) {
  __shared__ __align__(16) char sm[131072];

  const int tid  = threadIdx.x;
  const int lane = tid & 63;
  const int wave = tid >> 6;   // 0..7
  const int wm   = wave >> 2;  // 0..1
  const int wn   = wave & 3;   // 0..3
  const int quad = lane >> 4;
  const int l15  = lane & 15;

  // XCD-local mapping (R10-verified): XCD x owns mt in [x*Mx,(x+1)*Mx);
  // walks 4-nt groups of Mx*4 blocks -> live set A 4MB + B 2MB ~ one L2.
  const int bid = blockIdx.x;
  const int Mx  = Mtiles >> 3;
  const int xcd = bid & 7;
  const int wl  = bid >> 3;
  const int gsz = Mx << 2;
  const int grp = wl / gsz;
  const int rr  = wl - grp * gsz;
  const int mt  = xcd * Mx + (rr % Mx);
  const int nt  = (grp << 2) + (rr / Mx);
  const long m0 = (long)mt * 256;
  const long n0 = (long)nt * 256;

  const int srow = tid >> 3;
  const int sg   = (tid & 7) ^ (srow & 7);
  const __hip_bfloat16* aS = A  + (m0 + srow) * lda + sg * 8;
  const __hip_bfloat16* bS = Bt + (n0 + srow) * ldb + sg * 8;
  char* smc = (char*)sm;
  const int ldsOff = tid * 16;

  const int aRowB = (wm * 128 + l15) * 128;
  const int bRowB = 32768 + (wn * 64 + l15) * 128;
  const int sw    = (l15 & 7) << 4;
  const int cx0   = (quad * 16) ^ sw;
  const int cx1   = (64 + quad * 16) ^ sw;

  f32x4 acc[8][4] = {};

#define GLD_A(pp, kk, i)                                                   \
  gld16(aS + (long)(i) * 64 * lda + (kk),                                  \
        smc + (pp) * 65536 + (i) * 8192 + ldsOff);
#define GLD_B(pp, kk, i)                                                   \
  gld16(bS + (long)(i) * 64 * ldb + (kk),                                  \
        smc + (pp) * 65536 + 32768 + (i) * 8192 + ldsOff);

// 8-MFMA cluster: acc[accI..accI+3][accJ..accJ+1] += AR[0..3] x BR[0..1]
#define QCL(AR, BR, accI, accJ)                                            \
  __builtin_amdgcn_s_setprio(1);                                           \
  _Pragma("unroll") for (int it = 0; it < 4; ++it)                         \
      _Pragma("unroll") for (int jt = 0; jt < 2; ++jt)                     \
          acc[(accI) + it][(accJ) + jt] =                                  \
              __builtin_amdgcn_mfma_f32_16x16x32_bf16(                     \
                  AR[it], BR[jt], acc[(accI) + it][(accJ) + jt], 0, 0, 0); \
  __builtin_amdgcn_s_setprio(0);

  const int NT = K >> 6;
  // prologue: stage tiles 0 (buf0) and 1 (buf1) fully
#pragma unroll
  for (int i = 0; i < 4; ++i) { GLD_A(0, 0, i) GLD_B(0, 0, i) }
#pragma unroll
  for (int i = 0; i < 4; ++i) { GLD_A(1, 64, i) GLD_B(1, 64, i) }
  asm volatile("s_waitcnt vmcnt(8)" ::: "memory");  // tile 0 resident (mine)
  __builtin_amdgcn_s_barrier();                     // ...and everyone's
  asm volatile("" ::: "memory");

  // pipelined fragment registers (two ks-halves, statically indexed)
  bf16x8 a0k0[4], a1k0[4], a0k1[4], a1k1[4];
  bf16x8 b01k0[2], b23k0[2], b01k1[2], b23k1[2];
  // first batch for tile 0: b01_k0 + af0_k0
#pragma unroll
  for (int jt = 0; jt < 2; ++jt)
    b01k0[jt] = *(const bf16x8*)(smc + bRowB + jt * 2048 + cx0);
#pragma unroll
  for (int it = 0; it < 4; ++it)
    a0k0[it] = *(const bf16x8*)(smc + aRowB + it * 2048 + cx0);

  int p = 0;
  for (int t = 0; t < NT; ++t) {
    const char* base  = smc + p * 65536;
    const char* nbase = smc + (p ^ 1) * 65536;
    const long kk = (long)(t + 2) * 64;
    const bool pf = (t + 2 < NT);

    // s1: read b23_k0  (overlaps Q1_k0 issue below via in-flight lgkm)
#pragma unroll
    for (int jt = 0; jt < 2; ++jt)
      b23k0[jt] = *(const bf16x8*)(base + bRowB + (jt + 2) * 2048 + cx0);
    // s2: Q1_k0 = (m0,n0) half-k0
    QCL(a0k0, b01k0, 0, 0)
    // s3: read af1_k0
#pragma unroll
    for (int it = 0; it < 4; ++it)
      a1k0[it] = *(const bf16x8*)(base + aRowB + (4 + it) * 2048 + cx0);
    // s4: Q2_k0 = (m0,n1)
    QCL(a0k0, b23k0, 0, 2)
    // s5: read b01_k1 + af0_k1
#pragma unroll
    for (int jt = 0; jt < 2; ++jt)
      b01k1[jt] = *(const bf16x8*)(base + bRowB + jt * 2048 + cx1);
#pragma unroll
    for (int it = 0; it < 4; ++it)
      a0k1[it] = *(const bf16x8*)(base + aRowB + it * 2048 + cx1);
    // s6: Q4_k0 = (m1,n0)
    QCL(a1k0, b01k0, 4, 0)
    // s7: read b23_k1
#pragma unroll
    for (int jt = 0; jt < 2; ++jt)
      b23k1[jt] = *(const bf16x8*)(base + bRowB + (jt + 2) * 2048 + cx1);
    // s8: Q3_k0 = (m1,n1)
    QCL(a1k0, b23k0, 4, 2)
    // s9: read af1_k1
#pragma unroll
    for (int it = 0; it < 4; ++it)
      a1k1[it] = *(const bf16x8*)(base + aRowB + (4 + it) * 2048 + cx1);
    // s10: Q1_k1, s11: Q2_k1
    QCL(a0k1, b01k1, 0, 0)
    QCL(a0k1, b23k1, 0, 2)
    // s12: all my buf-p reads done -> barrier -> stage t+2 into buf p
    asm volatile("s_waitcnt lgkmcnt(0)" ::: "memory");
    __builtin_amdgcn_s_barrier();
    asm volatile("" ::: "memory");
    if (pf) {
      GLD_A(p, kk, 0) GLD_A(p, kk, 1) GLD_A(p, kk, 2) GLD_A(p, kk, 3)
      GLD_B(p, kk, 0) GLD_B(p, kk, 1) GLD_B(p, kk, 2) GLD_B(p, kk, 3)
    }
    // s13: Q4_k1 (hides staging issue)
    QCL(a1k1, b01k1, 4, 0)
    // s14: tile t+1 resident for all waves
    if (pf) {
      asm volatile("s_waitcnt vmcnt(8)" ::: "memory");
    } else {
      asm volatile("s_waitcnt vmcnt(0)" ::: "memory");
    }
    __builtin_amdgcn_s_barrier();
    asm volatile("" ::: "memory");
    // s15: first batch for tile t+1 (hides under Q3_k1)
    if (t + 1 < NT) {
#pragma unroll
      for (int jt = 0; jt < 2; ++jt)
        b01k0[jt] = *(const bf16x8*)(nbase + bRowB + jt * 2048 + cx0);
#pragma unroll
      for (int it = 0; it < 4; ++it)
        a0k0[it] = *(const bf16x8*)(nbase + aRowB + it * 2048 + cx0);
    }
    // s16: Q3_k1
    QCL(a1k1, b23k1, 4, 2)
    p ^= 1;
  }
#undef GLD_A
#undef GLD_B
#undef QCL

  if constexpr (EPI == 7) {
    __hip_bfloat16* Cb = (__hip_bfloat16*)Cp;
    const long slab  = (n0 >> 10) * 16777216;
    const long ncol0 = (n0 & 1023) + wn * 64 + l15;
#pragma unroll
    for (int it = 0; it < 8; ++it) {
#pragma unroll
      for (int i = 0; i < 4; ++i) {
        const long gm = m0 + wm * 128 + it * 16 + quad * 4 + i;
        __hip_bfloat16* rowp = Cb + slab + gm * 1024 + ncol0;
#pragma unroll
        for (int jt = 0; jt < 4; ++jt)
          rowp[jt * 16] = (__hip_bfloat16)acc[it][jt][i];
      }
    }
  } else if constexpr (EPI == 5) {
    float* Cf = (float*)Cp;
    float bv[4];
#pragma unroll
    for (int jt = 0; jt < 4; ++jt)
      bv[jt] = bias[n0 + wn * 64 + jt * 16 + l15];
#pragma unroll
    for (int it = 0; it < 8; ++it) {
#pragma unroll
      for (int i = 0; i < 4; ++i) {
        const long gm = m0 + wm * 128 + it * 16 + quad * 4 + i;
        float* rowp = Cf + gm * ldc + n0 + wn * 64 + l15;
#pragma unroll
        for (int jt = 0; jt < 4; ++jt)
          rowp[jt * 16] = acc[it][jt][i] + bv[jt];
      }
    }
  }
}

// ---------------------------------------------------------------------------
// favor_kv: fused kp = relu(projb.K^T)+eps ; kvxT(288x80) += kp . [V;1]^T
// (unchanged from R10-verified)
// ---------------------------------------------------------------------------
__global__ void __launch_bounds__(512, 2)
favor_kv(const __hip_bfloat16* __restrict__ Kb,
         const __hip_bfloat16* __restrict__ Vb,
         const __hip_bfloat16* __restrict__ projb_g,
         float* __restrict__ kvp) {
  __shared__ __align__(16) char sm[147456];
  char* Kt = sm;
  char* Pj = sm + 16384;
  char* KP = sm + 53248;
  char* VT = sm + 126976;

  const int tid  = threadIdx.x;
  const int lane = tid & 63;
  const int wave = tid >> 6;
  const int quad = lane >> 4;
  const int l15  = lane & 15;
  const int swL  = (l15 & 7) << 4;

  const int bh   = blockIdx.x & 63;
  const int slab = blockIdx.x >> 6;  // 0..3
  const int b    = bh >> 4, h = bh & 15;
  const long rowbase = (long)b * 4096 + (long)slab * 1024;

  for (int p = 0; p < 5; ++p) {
    const int idx = p * 512 + tid;
    if (idx < 2304) {
      const int r = idx >> 3, g = (idx & 7) ^ (r & 7);
      gld16(projb_g + r * 64 + g * 8, Pj + p * 8192 + tid * 16);
    }
  }
  {
    unsigned short* vth = (unsigned short*)(VT + 64 * 256);
    const unsigned short one_bf = 0x3F80;
    for (int i = tid; i < 2048; i += 512) vth[i] = (i < 128) ? one_bf : 0;
  }

  const int rS = tid >> 3, gS = (tid & 7) ^ (rS & 7);
  const int rS2 = rS + 64, gS2 = (tid & 7) ^ (rS2 & 7);
  const int nl = tid >> 3, seg = tid & 7;
  gld16(Kb + (rowbase + rS) * 1024 + h * 64 + gS * 8, Kt + tid * 16);
  gld16(Kb + (rowbase + rS2) * 1024 + h * 64 + gS2 * 8, Kt + 8192 + tid * 16);
  u16x8 vc0 = *(const u16x8*)(Vb + (rowbase + nl) * 1024 + h * 64 + seg * 8);
  u16x8 vc1 =
      *(const u16x8*)(Vb + (rowbase + 64 + nl) * 1024 + h * 64 + seg * 8);

  const int wm1 = wave & 3;
  const int wn1 = wave >> 2;
  const int nJ = (wave < 2) ? 3 : 2;

  f32x4 acc2[3][5] = {};

  for (int t = 0; t < 8; ++t) {
    asm volatile("s_waitcnt vmcnt(0)" ::: "memory");
    __builtin_amdgcn_s_barrier();
    asm volatile("" ::: "memory");
    {
#pragma unroll
      for (int j = 0; j < 8; ++j) {
        const int d = seg * 8 + j;
        const int s = ((d & 7) ^ ((d >> 3) & 7)) << 4;
        *(unsigned short*)(VT + d * 256 + ((nl * 2) ^ s)) = vc0[j];
        *(unsigned short*)(VT + d * 256 + (((nl + 64) * 2) ^ s)) = vc1[j];
      }
    }
    f32x4 acc1[2][9] = {};
#pragma unroll
    for (int ks = 0; ks < 2; ++ks) {
      const int cb = ks * 64 + quad * 16;
      bf16x8 af[2];
#pragma unroll
      for (int fm = 0; fm < 2; ++fm)
        af[fm] = *(const bf16x8*)(Kt + (wm1 * 32 + fm * 16 + l15) * 128 +
                                  (cb ^ swL));
      bf16x8 bfr[9];
#pragma unroll
      for (int fn = 0; fn < 9; ++fn)
        bfr[fn] = *(const bf16x8*)(Pj + (wn1 * 144 + fn * 16 + l15) * 128 +
                                   (cb ^ swL));
#pragma unroll
      for (int fm = 0; fm < 2; ++fm)
#pragma unroll
        for (int fn = 0; fn < 9; ++fn)
          acc1[fm][fn] = __builtin_amdgcn_mfma_f32_16x16x32_bf16(
              af[fm], bfr[fn], acc1[fm][fn], 0, 0, 0);
    }
#pragma unroll
    for (int fm = 0; fm < 2; ++fm) {
      const int nb = (wm1 * 32 + fm * 16 + quad * 4) * 2;
#pragma unroll
      for (int fn = 0; fn < 9; ++fn) {
        const int r = wn1 * 144 + fn * 16 + l15;
        const bool ok = (r < 266);
        union { __hip_bfloat16 hh[4]; uint2 u; } pk;
#pragma unroll
        for (int ii = 0; ii < 4; ++ii) {
          float v = acc1[fm][fn][ii];
          v = ok ? (fmaxf(v, 0.f) + EPS_F) : 0.f;
          pk.hh[ii] = (__hip_bfloat16)v;
        }
        *(uint2*)(KP + r * 256 + (nb ^ ((r & 7) << 4))) = pk.u;
      }
    }
    asm volatile("s_waitcnt lgkmcnt(0)" ::: "memory");
    __builtin_amdgcn_s_barrier();
    asm volatile("" ::: "memory");
    if (t < 7) {
      const long n1 = (long)(t + 1) * 128;
      gld16(Kb + (rowbase + n1 + rS) * 1024 + h * 64 + gS * 8, Kt + tid * 16);
      gld16(Kb + (rowbase + n1 + rS2) * 1024 + h * 64 + gS2 * 8,
            Kt + 8192 + tid * 16);
      vc0 = *(const u16x8*)(Vb + (rowbase + n1 + nl) * 1024 + h * 64 +
                            seg * 8);
      vc1 = *(const u16x8*)(Vb + (rowbase + n1 + 64 + nl) * 1024 + h * 64 +
                            seg * 8);
    }
#pragma unroll
    for (int ks = 0; ks < 4; ++ks) {
      const int cb = ks * 64 + quad * 16;
      bf16x8 bfr[5];
#pragma unroll
      for (int fd = 0; fd < 5; ++fd) {
        const int d = fd * 16 + l15;
        const int s = ((d & 7) ^ ((d >> 3) & 7)) << 4;
        bfr[fd] = *(const bf16x8*)(VT + d * 256 + (cb ^ s));
      }
#pragma unroll
      for (int j = 0; j < 3; ++j) {
        if (j < nJ) {
          const int r = (wave + 8 * j) * 16 + l15;
          const bf16x8 af =
              *(const bf16x8*)(KP + r * 256 + (cb ^ ((r & 7) << 4)));
#pragma unroll
          for (int fd = 0; fd < 5; ++fd)
            acc2[j][fd] = __builtin_amdgcn_mfma_f32_16x16x32_bf16(
                af, bfr[fd], acc2[j][fd], 0, 0, 0);
        }
      }
    }
  }
  float* dst = kvp + (long)blockIdx.x * 23040;
#pragma unroll
  for (int j = 0; j < 3; ++j) {
    if (j < nJ) {
      const int rb = (wave + 8 * j) * 16 + quad * 4;
#pragma unroll
      for (int fd = 0; fd < 5; ++fd) {
        const int d = fd * 16 + l15;
#pragma unroll
        for (int ii = 0; ii < 4; ++ii)
          dst[(long)(rb + ii) * 80 + d] = acc2[j][fd][ii];
      }
    }
  }
}

// kvxb[bh][d][r] bf16 = sum_slab kvp[slab][bh][r][d]
__global__ void __launch_bounds__(256)
finalize_kvx2(const float* __restrict__ kvp,
              __hip_bfloat16* __restrict__ kvxb) {
  __shared__ float lds_f[23040];
  const int bh = blockIdx.x, t = threadIdx.x;
  for (int p = 0; p < 90; ++p) {
    const int idx = p * 256 + t;
    float s = 0.f;
#pragma unroll
    for (int sl = 0; sl < 4; ++sl)
      s += kvp[(long)(sl * 64 + bh) * 23040 + idx];
    lds_f[idx] = s;
  }
  __syncthreads();
  for (int p = 0; p < 90; ++p) {
    const int idx = p * 256 + t;
    const int d = idx / 288, r = idx % 288;
    kvxb[(long)bh * 23040 + idx] = (__hip_bfloat16)lds_f[r * 80 + d];
  }
}

// ---------------------------------------------------------------------------
// favor_out: qp = relu(Q.projb^T)+eps ; out = (qp . kvxb^T)/denom, merged
// (unchanged from R10-verified)
// ---------------------------------------------------------------------------
__global__ void __launch_bounds__(512, 2)
favor_out(const __hip_bfloat16* __restrict__ Qb,
          const __hip_bfloat16* __restrict__ kvxb_g,
          const __hip_bfloat16* __restrict__ projb_g,
          __hip_bfloat16* __restrict__ outm) {
  __shared__ __align__(16) char sm[160512];
  char* Pj = sm;
  char* KX = sm + 36864;
  char* QP = sm + 84224;
  float* Dsh = (float*)(sm + 160000);

  const int tid  = threadIdx.x;
  const int lane = tid & 63;
  const int wave = tid >> 6;
  const int quad = lane >> 4;
  const int l15  = lane & 15;
  const int swL  = (l15 & 7) << 4;

  const int bh  = blockIdx.x >> 3;
  const int rb8 = blockIdx.x & 7;
  const int b = bh >> 4, h = bh & 15;
  const long rowbase = (long)b * 4096 + (long)rb8 * 512;

  for (int p = 0; p < 5; ++p) {
    const int idx = p * 512 + tid;
    if (idx < 2304) {
      const int r = idx >> 3, g = (idx & 7) ^ (r & 7);
      gld16(projb_g + r * 64 + g * 8, Pj + p * 8192 + tid * 16);
    }
  }
  {
    const __hip_bfloat16* src = kvxb_g + (long)bh * 23040;
#pragma unroll
    for (int p = 0; p < 6; ++p) {
      const int idx = p * 512 + tid;
      if (idx < 2880) {
        const int d = idx / 36, g = idx % 36;
        const bf16x8 v = *(const bf16x8*)(src + d * 288 + g * 8);
        *(bf16x8*)(KX + d * 592 + g * 16) = v;
      }
    }
  }
  const int rS = tid >> 3, gS = (tid & 7) ^ (rS & 7);
  const int rS2 = rS + 64, gS2 = (tid & 7) ^ (rS2 & 7);
  u16x8 qv0 = *(const u16x8*)(Qb + (rowbase + rS) * 1024 + h * 64 + gS * 8);
  u16x8 qv1 = *(const u16x8*)(Qb + (rowbase + rS2) * 1024 + h * 64 + gS2 * 8);

  const int wm1 = wave >> 2;
  const int wn1 = wave & 3;

  for (int s = 0; s < 4; ++s) {
    *(u16x8*)(QP + tid * 16) = qv0;
    *(u16x8*)(QP + 8192 + tid * 16) = qv1;
    asm volatile("s_waitcnt lgkmcnt(0)" ::: "memory");
    if (s == 0) asm volatile("s_waitcnt vmcnt(0)" ::: "memory");
    __builtin_amdgcn_s_barrier();
    asm volatile("" ::: "memory");
    f32x4 acc1[9][2] = {};
#pragma unroll
    for (int ks = 0; ks < 2; ++ks) {
      const int cb = ks * 64 + quad * 16;
      bf16x8 bfr[2];
#pragma unroll
      for (int fn = 0; fn < 2; ++fn)
        bfr[fn] = *(const bf16x8*)(QP + (wn1 * 32 + fn * 16 + l15) * 128 +
                                   (cb ^ swL));
      bf16x8 af[9];
#pragma unroll
      for (int fm = 0; fm < 9; ++fm)
        af[fm] = *(const bf16x8*)(Pj + (wm1 * 144 + fm * 16 + l15) * 128 +
                                  (cb ^ swL));
#pragma unroll
      for (int fm = 0; fm < 9; ++fm)
#pragma unroll
        for (int fn = 0; fn < 2; ++fn)
          acc1[fm][fn] = __builtin_amdgcn_mfma_f32_16x16x32_bf16(
              af[fm], bfr[fn], acc1[fm][fn], 0, 0, 0);
    }
    if (s < 3) {
      const long n1 = (long)(s + 1) * 128;
      qv0 = *(const u16x8*)(Qb + (rowbase + n1 + rS) * 1024 + h * 64 + gS * 8);
      qv1 = *(const u16x8*)(Qb + (rowbase + n1 + rS2) * 1024 + h * 64 +
                            gS2 * 8);
    }
    __builtin_amdgcn_s_barrier();
    asm volatile("" ::: "memory");
#pragma unroll
    for (int fm = 0; fm < 9; ++fm) {
      const int r0 = wm1 * 144 + fm * 16 + quad * 4;
#pragma unroll
      for (int fn = 0; fn < 2; ++fn) {
        const int n = wn1 * 32 + fn * 16 + l15;
        union { __hip_bfloat16 hh[4]; uint2 u; } pk;
#pragma unroll
        for (int ii = 0; ii < 4; ++ii) {
          float v = acc1[fm][fn][ii];
          v = (r0 + ii < 266) ? (fmaxf(v, 0.f) + EPS_F) : 0.f;
          pk.hh[ii] = (__hip_bfloat16)v;
        }
        *(uint2*)(QP + n * 592 + r0 * 2) = pk.u;
      }
    }
    asm volatile("s_waitcnt lgkmcnt(0)" ::: "memory");
    __builtin_amdgcn_s_barrier();
    asm volatile("" ::: "memory");
    f32x4 acc2[5] = {};
#pragma unroll
    for (int ks = 0; ks < 9; ++ks) {
      const int cb = ks * 64 + quad * 16;
      const bf16x8 af = *(const bf16x8*)(QP + (wave * 16 + l15) * 592 + cb);
      bf16x8 bfr[5];
#pragma unroll
      for (int fd = 0; fd < 5; ++fd)
        bfr[fd] = *(const bf16x8*)(KX + (fd * 16 + l15) * 592 + cb);
#pragma unroll
      for (int fd = 0; fd < 5; ++fd)
        acc2[fd] = __builtin_amdgcn_mfma_f32_16x16x32_bf16(af, bfr[fd],
                                                           acc2[fd], 0, 0, 0);
    }
    if (l15 == 0) {
#pragma unroll
      for (int ii = 0; ii < 4; ++ii)
        Dsh[wave * 16 + quad * 4 + ii] = acc2[4][ii];
    }
    asm volatile("s_waitcnt lgkmcnt(0)" ::: "memory");
    __builtin_amdgcn_s_barrier();
    asm volatile("" ::: "memory");
#pragma unroll
    for (int ii = 0; ii < 4; ++ii) {
      const int nloc = wave * 16 + quad * 4 + ii;
      const float den = Dsh[nloc];
      const float dinv = (den > 1e-30f) ? (1.f / den) : 0.f;
      __hip_bfloat16* rowp =
          outm + (rowbase + (long)s * 128 + nloc) * 1024 + h * 64;
#pragma unroll
      for (int fd = 0; fd < 4; ++fd)
        rowp[fd * 16 + l15] = (__hip_bfloat16)(acc2[fd][ii] * dinv);
    }
  }
}

// xb = bf16(x), 8 elements/thread
__global__ void cvt_x(const float* __restrict__ x,
                      __hip_bfloat16* __restrict__ xb) {
  const long i = ((long)blockIdx.x * 256 + threadIdx.x) * 8;
  const float4 f0 = *(const float4*)(x + i);
  const float4 f1 = *(const float4*)(x + i + 4);
  union { __hip_bfloat16 h[8]; uint4 u; } r;
  r.h[0] = (__hip_bfloat16)f0.x; r.h[1] = (__hip_bfloat16)f0.y;
  r.h[2] = (__hip_bfloat16)f0.z; r.h[3] = (__hip_bfloat16)f0.w;
  r.h[4] = (__hip_bfloat16)f1.x; r.h[5] = (__hip_bfloat16)f1.y;
  r.h[6] = (__hip_bfloat16)f1.z; r.h[7] = (__hip_bfloat16)f1.w;
  *(uint4*)(xb + i) = r.u;
}

// all 4 weight transposes in one launch: z in 0..3 picks src/dst.
__global__ void transpose_w4(const float* __restrict__ s0,
                             const float* __restrict__ s1,
                             const float* __restrict__ s2,
                             const float* __restrict__ s3,
                             __hip_bfloat16* __restrict__ dq,
                             __hip_bfloat16* __restrict__ dwo) {
  __shared__ float t[32][33];
  const int z = blockIdx.z;
  const float* src = (z == 0) ? s0 : (z == 1) ? s1 : (z == 2) ? s2 : s3;
  __hip_bfloat16* dst = (z < 3) ? (dq + (long)z * 1048576) : dwo;
  const int k0 = blockIdx.x * 32, n0 = blockIdx.y * 32;
  const int tx = threadIdx.x & 31, ty = threadIdx.x >> 5;
#pragma unroll
  for (int i = 0; i < 4; ++i)
    t[ty + i * 8][tx] = src[(long)(k0 + ty + i * 8) * 1024 + n0 + tx];
  __syncthreads();
#pragma unroll
  for (int i = 0; i < 4; ++i)
    dst[(long)(n0 + ty + i * 8) * 1024 + k0 + tx] =
        (__hip_bfloat16)t[tx][ty + i * 8];
}

// projb (288x64 bf16): rows<266 = bf16(proj), rows 266..287 exact zero.
__global__ void prep_proj(const float* __restrict__ proj,
                          __hip_bfloat16* __restrict__ projb) {
  const int i = blockIdx.x * 256 + threadIdx.x;
  if (i < 288 * 64) {
    const int r = i >> 6;
    __hip_bfloat16 v = (__hip_bfloat16)0.f;
    if (r < 266) v = (__hip_bfloat16)proj[i];
    projb[i] = v;
  }
}

// ---------------------------------------------------------------------------
extern "C" void kernel_launch(void* const* d_in, const int* in_sizes, int n_in,
                              void* d_out, int out_size, void* d_ws,
                              size_t ws_size, hipStream_t stream) {
  const float* x    = (const float*)d_in[0];
  const float* Wq   = (const float*)d_in[1];
  const float* Wk   = (const float*)d_in[2];
  const float* Wv   = (const float*)d_in[3];
  const float* Wo   = (const float*)d_in[4];
  const float* bo   = (const float*)d_in[5];
  const float* proj = (const float*)d_in[6];
  float* out = (float*)d_out;
  char* ws = (char*)d_ws;

  // ws layout (bytes); total 135,630,848 (proven fit)
  constexpr long o_wqkvt = 0;            // 6,291,456
  constexpr long o_wot   = 6291456;      // 2,097,152
  constexpr long o_projb = 8388608;      // 36,864
  constexpr long o_Qb    = 8425472;      // 33,554,432
  constexpr long o_Kb    = 41979904;     // 33,554,432 (alias outm)
  constexpr long o_Vb    = 75534336;     // 33,554,432
  constexpr long o_xb    = 109088768;    // 33,554,432 (alias kvp/kvxb)
  constexpr long o_kvp   = 109088768;    // 4*64*23040*4 = 23,592,960
  constexpr long o_kvxb  = 132681728;    // 64*23040*2   =  2,949,120

  __hip_bfloat16* wqkvt = (__hip_bfloat16*)(ws + o_wqkvt);
  __hip_bfloat16* wot   = (__hip_bfloat16*)(ws + o_wot);
  __hip_bfloat16* projb = (__hip_bfloat16*)(ws + o_projb);
  __hip_bfloat16* Qb    = (__hip_bfloat16*)(ws + o_Qb);
  __hip_bfloat16* Kb    = (__hip_bfloat16*)(ws + o_Kb);
  __hip_bfloat16* Vb    = (__hip_bfloat16*)(ws + o_Vb);
  __hip_bfloat16* xb    = (__hip_bfloat16*)(ws + o_xb);
  float*          kvp   = (float*)(ws + o_kvp);
  __hip_bfloat16* kvxb  = (__hip_bfloat16*)(ws + o_kvxb);
  __hip_bfloat16* outm  = Kb;  // alias: Kb dead after favor_kv

  // prep
  cvt_x<<<8192, 256, 0, stream>>>(x, xb);
  transpose_w4<<<dim3(32, 32, 4), 256, 0, stream>>>(Wq, Wk, Wv, Wo, wqkvt,
                                                    wot);
  prep_proj<<<72, 256, 0, stream>>>(proj, projb);

  // S1 fused: [Qb|Kb|Vb] = xb . wqkvt^T  (256^2 pipelined GEMM, EPI7)
  gemm256<7><<<768, 512, 0, stream>>>(xb, 1024, wqkvt, 1024, Qb, 0, 64, 12,
                                      1024, nullptr);

  // phase A fused: kvp partials, then reduce+transpose to kvxb
  favor_kv<<<256, 512, 0, stream>>>(Kb, Vb, projb, kvp);
  finalize_kvx2<<<64, 256, 0, stream>>>(kvp, kvxb);

  // phase B fused: outm = (relu(Q.projb^T)+eps) . kvxb^T / denom, merged
  favor_out<<<512, 512, 0, stream>>>(Qb, kvxb, projb, outm);

  // S5: out(f32) = outm . wot^T + bo  (256^2 pipelined GEMM, EPI5)
  gemm256<5><<<256, 512, 0, stream>>>(outm, 1024, wot, 1024, out, 1024, 64, 4,
                                      1024, bo);
}

// Round 7
// 367.307 us; speedup vs baseline: 2.2763x; 1.0346x over previous
//
#include <hip/hip_runtime.h>
#include <hip/hip_bf16.h>

// ---------------------------------------------------------------------------
// Performer (FAVOR+) attention, MI355X gfx950.  f32 I/O, bf16 MFMA internals.
// R14: S1/S5 gemm256 kept from R13 (verified, 109 µs).  Changes:
//  (1) favor_kv rebuilt: KVBLK=64, double-buffered Kt/KP/VT (same 147KB),
//      ONE barrier + ONE vmcnt(0) per tile; phase t = {VT(t) scatter,
//      prefetch t+1, GEMM1(t), epi(t)->KP[t&1], GEMM2(t-1) from buffers
//      (t-1)&1}.  GEMM1/GEMM2 MFMAs run back-to-back; drains amortized.
//      Global n-accumulation order unchanged -> bit-identical kvp.
//  (2) finalize_kvx2: 64 -> 256 blocks (bh x 4 d-quarters), padded-LDS
//      transpose (conflict-free), ~3x faster.
//  (3) prep_proj merged into transpose kernel (z==4), one fewer launch.
//   prep:  wqkvt(3072x1024)=bf16([Wq|Wk|Wv]^T); wot=bf16(Wo^T); projb padded
//   S1:    [Qb|Kb|Vb](16384x1024 bf16 each) = xb . wqkvt^T   (gemm256 EPI7)
//   favor_kv (grid 64bh x 4slab): kvxT(288x80) += kp . [V;1]^T per 64 rows
//   finalize_kvx2: kvxb[bh][80][288] bf16 = transpose(sum_slab kvp)
//   favor_out (grid 64bh x 8): qp = relu(Q.projb^T)+eps; out = qp.kvxb^T
//       /denom(col 64); merged-head bf16 store
//   S5:    out(f32) = outm . wot^T + bo (gemm256 EPI5)
// Aliases: xb==kvp/kvxb region (dead after S1); outm==Kb (dead after A).
// ---------------------------------------------------------------------------

typedef __bf16 bf16x8 __attribute__((ext_vector_type(8)));
typedef unsigned short u16x8 __attribute__((ext_vector_type(8)));
typedef float  f32x4  __attribute__((ext_vector_type(4)));

#define EPS_F 1e-3f

__device__ __forceinline__ void gld16(const void* g, void* l) {
  __builtin_amdgcn_global_load_lds(
      (const __attribute__((address_space(1))) void*)g,
      (__attribute__((address_space(3))) void*)l, 16, 0, 0);
}

// ---------------------------------------------------------------------------
// gemm256: 256x256 tile, BK=64, 8 waves (2M x 4N), per-wave 128x64 output.
// R13-verified within-wave pipelined K-loop.  Unchanged.
// Requires M%256==0, N%256==0, K%64==0 (K>=128), Mtiles%8==0, Ntiles%4==0.
// ---------------------------------------------------------------------------
template <int EPI>
__global__ void __launch_bounds__(512, 2)
gemm256(const __hip_bfloat16* __restrict__ A, long lda,
        const __hip_bfloat16* __restrict__ Bt, long ldb,
        void* __restrict__ Cp, long ldc,
        int Mtiles, int Ntiles, int K, const float* __restrict__ bias) {
  __shared__ __align__(16) char sm[131072];

  const int tid  = threadIdx.x;
  const int lane = tid & 63;
  const int wave = tid >> 6;   // 0..7
  const int wm   = wave >> 2;  // 0..1
  const int wn   = wave & 3;   // 0..3
  const int quad = lane >> 4;
  const int l15  = lane & 15;

  const int bid = blockIdx.x;
  const int Mx  = Mtiles >> 3;
  const int xcd = bid & 7;
  const int wl  = bid >> 3;
  const int gsz = Mx << 2;
  const int grp = wl / gsz;
  const int rr  = wl - grp * gsz;
  const int mt  = xcd * Mx + (rr % Mx);
  const int nt  = (grp << 2) + (rr / Mx);
  const long m0 = (long)mt * 256;
  const long n0 = (long)nt * 256;

  const int srow = tid >> 3;
  const int sg   = (tid & 7) ^ (srow & 7);
  const __hip_bfloat16* aS = A  + (m0 + srow) * lda + sg * 8;
  const __hip_bfloat16* bS = Bt + (n0 + srow) * ldb + sg * 8;
  char* smc = (char*)sm;
  const int ldsOff = tid * 16;

  const int aRowB = (wm * 128 + l15) * 128;
  const int bRowB = 32768 + (wn * 64 + l15) * 128;
  const int sw    = (l15 & 7) << 4;
  const int cx0   = (quad * 16) ^ sw;
  const int cx1   = (64 + quad * 16) ^ sw;

  f32x4 acc[8][4] = {};

#define GLD_A(pp, kk, i)                                                   \
  gld16(aS + (long)(i) * 64 * lda + (kk),                                  \
        smc + (pp) * 65536 + (i) * 8192 + ldsOff);
#define GLD_B(pp, kk, i)                                                   \
  gld16(bS + (long)(i) * 64 * ldb + (kk),                                  \
        smc + (pp) * 65536 + 32768 + (i) * 8192 + ldsOff);

#define QCL(AR, BR, accI, accJ)                                            \
  __builtin_amdgcn_s_setprio(1);                                           \
  _Pragma("unroll") for (int it = 0; it < 4; ++it)                         \
      _Pragma("unroll") for (int jt = 0; jt < 2; ++jt)                     \
          acc[(accI) + it][(accJ) + jt] =                                  \
              __builtin_amdgcn_mfma_f32_16x16x32_bf16(                     \
                  AR[it], BR[jt], acc[(accI) + it][(accJ) + jt], 0, 0, 0); \
  __builtin_amdgcn_s_setprio(0);

  const int NT = K >> 6;
#pragma unroll
  for (int i = 0; i < 4; ++i) { GLD_A(0, 0, i) GLD_B(0, 0, i) }
#pragma unroll
  for (int i = 0; i < 4; ++i) { GLD_A(1, 64, i) GLD_B(1, 64, i) }
  asm volatile("s_waitcnt vmcnt(8)" ::: "memory");
  __builtin_amdgcn_s_barrier();
  asm volatile("" ::: "memory");

  bf16x8 a0k0[4], a1k0[4], a0k1[4], a1k1[4];
  bf16x8 b01k0[2], b23k0[2], b01k1[2], b23k1[2];
#pragma unroll
  for (int jt = 0; jt < 2; ++jt)
    b01k0[jt] = *(const bf16x8*)(smc + bRowB + jt * 2048 + cx0);
#pragma unroll
  for (int it = 0; it < 4; ++it)
    a0k0[it] = *(const bf16x8*)(smc + aRowB + it * 2048 + cx0);

  int p = 0;
  for (int t = 0; t < NT; ++t) {
    const char* base  = smc + p * 65536;
    const char* nbase = smc + (p ^ 1) * 65536;
    const long kk = (long)(t + 2) * 64;
    const bool pf = (t + 2 < NT);

#pragma unroll
    for (int jt = 0; jt < 2; ++jt)
      b23k0[jt] = *(const bf16x8*)(base + bRowB + (jt + 2) * 2048 + cx0);
    QCL(a0k0, b01k0, 0, 0)
#pragma unroll
    for (int it = 0; it < 4; ++it)
      a1k0[it] = *(const bf16x8*)(base + aRowB + (4 + it) * 2048 + cx0);
    QCL(a0k0, b23k0, 0, 2)
#pragma unroll
    for (int jt = 0; jt < 2; ++jt)
      b01k1[jt] = *(const bf16x8*)(base + bRowB + jt * 2048 + cx1);
#pragma unroll
    for (int it = 0; it < 4; ++it)
      a0k1[it] = *(const bf16x8*)(base + aRowB + it * 2048 + cx1);
    QCL(a1k0, b01k0, 4, 0)
#pragma unroll
    for (int jt = 0; jt < 2; ++jt)
      b23k1[jt] = *(const bf16x8*)(base + bRowB + (jt + 2) * 2048 + cx1);
    QCL(a1k0, b23k0, 4, 2)
#pragma unroll
    for (int it = 0; it < 4; ++it)
      a1k1[it] = *(const bf16x8*)(base + aRowB + (4 + it) * 2048 + cx1);
    QCL(a0k1, b01k1, 0, 0)
    QCL(a0k1, b23k1, 0, 2)
    asm volatile("s_waitcnt lgkmcnt(0)" ::: "memory");
    __builtin_amdgcn_s_barrier();
    asm volatile("" ::: "memory");
    if (pf) {
      GLD_A(p, kk, 0) GLD_A(p, kk, 1) GLD_A(p, kk, 2) GLD_A(p, kk, 3)
      GLD_B(p, kk, 0) GLD_B(p, kk, 1) GLD_B(p, kk, 2) GLD_B(p, kk, 3)
    }
    QCL(a1k1, b01k1, 4, 0)
    if (pf) {
      asm volatile("s_waitcnt vmcnt(8)" ::: "memory");
    } else {
      asm volatile("s_waitcnt vmcnt(0)" ::: "memory");
    }
    __builtin_amdgcn_s_barrier();
    asm volatile("" ::: "memory");
    if (t + 1 < NT) {
#pragma unroll
      for (int jt = 0; jt < 2; ++jt)
        b01k0[jt] = *(const bf16x8*)(nbase + bRowB + jt * 2048 + cx0);
#pragma unroll
      for (int it = 0; it < 4; ++it)
        a0k0[it] = *(const bf16x8*)(nbase + aRowB + it * 2048 + cx0);
    }
    QCL(a1k1, b23k1, 4, 2)
    p ^= 1;
  }
#undef GLD_A
#undef GLD_B
#undef QCL

  if constexpr (EPI == 7) {
    __hip_bfloat16* Cb = (__hip_bfloat16*)Cp;
    const long slab  = (n0 >> 10) * 16777216;
    const long ncol0 = (n0 & 1023) + wn * 64 + l15;
#pragma unroll
    for (int it = 0; it < 8; ++it) {
#pragma unroll
      for (int i = 0; i < 4; ++i) {
        const long gm = m0 + wm * 128 + it * 16 + quad * 4 + i;
        __hip_bfloat16* rowp = Cb + slab + gm * 1024 + ncol0;
#pragma unroll
        for (int jt = 0; jt < 4; ++jt)
          rowp[jt * 16] = (__hip_bfloat16)acc[it][jt][i];
      }
    }
  } else if constexpr (EPI == 5) {
    float* Cf = (float*)Cp;
    float bv[4];
#pragma unroll
    for (int jt = 0; jt < 4; ++jt)
      bv[jt] = bias[n0 + wn * 64 + jt * 16 + l15];
#pragma unroll
    for (int it = 0; it < 8; ++it) {
#pragma unroll
      for (int i = 0; i < 4; ++i) {
        const long gm = m0 + wm * 128 + it * 16 + quad * 4 + i;
        float* rowp = Cf + gm * ldc + n0 + wn * 64 + l15;
#pragma unroll
        for (int jt = 0; jt < 4; ++jt)
          rowp[jt * 16] = acc[it][jt][i] + bv[jt];
      }
    }
  }
}

// ---------------------------------------------------------------------------
// favor_kv (R14): KVBLK=64, double-buffered, 1 barrier + 1 vmcnt(0)/tile.
// Per phase t: VT[q] scatter | prefetch K/V(t+1) | GEMM1(t) 64n x 288r |
// epi -> KP[q] | GEMM2(t-1) from KP/VT[q^1].  16 tiles of 64 rows.
// LDS: Pj 288x128B | Kt 2x8K | KP 2x(288x128B) | VT 2x(80x128B) = 147456.
// Buffer recycling proof: KP[q] read by GEMM2 in phase t-1 (tile t-2 data,
// parity q), written by epi in phase t; separated by the phase barrier.
// ---------------------------------------------------------------------------
__global__ void __launch_bounds__(512, 2)
favor_kv(const __hip_bfloat16* __restrict__ Kb,
         const __hip_bfloat16* __restrict__ Vb,
         const __hip_bfloat16* __restrict__ projb_g,
         float* __restrict__ kvp) {
  __shared__ __align__(16) char sm[147456];
  char* Pj  = sm;            // 36864
  char* KtB = sm + 36864;    // 2 x 8192
  char* KPB = sm + 53248;    // 2 x 36864
  char* VTB = sm + 126976;   // 2 x 10240

  const int tid  = threadIdx.x;
  const int lane = tid & 63;
  const int wave = tid >> 6;
  const int quad = lane >> 4;
  const int l15  = lane & 15;
  const int swL  = (l15 & 7) << 4;

  const int bh   = blockIdx.x & 63;
  const int slab = blockIdx.x >> 6;  // 0..3
  const int b    = bh >> 4, h = bh & 15;
  const long rowbase = (long)b * 4096 + (long)slab * 1024;

  // stage projb (pre-swizzled source)
  for (int p = 0; p < 5; ++p) {
    const int idx = p * 512 + tid;
    if (idx < 2304) {
      const int r = idx >> 3, g = (idx & 7) ^ (r & 7);
      gld16(projb_g + r * 64 + g * 8, Pj + idx * 16);
    }
  }
  // VT rows 64..79 (both buffers): row 64 = ones (64 entries), rest zero
#pragma unroll
  for (int q = 0; q < 2; ++q) {
    unsigned short* vth = (unsigned short*)(VTB + q * 10240 + 64 * 128);
    for (int i = tid; i < 1024; i += 512) vth[i] = (i < 64) ? 0x3F80 : 0;
  }

  // tile-0 prefetch: K -> Kt[0] (gld_lds), V -> regs
  const int rK = tid >> 3, gK = (tid & 7) ^ (rK & 7);
  const int nl = tid >> 3, seg = tid & 7;
  gld16(Kb + (rowbase + rK) * 1024 + h * 64 + gK * 8, KtB + tid * 16);
  u16x8 vc = *(const u16x8*)(Vb + (rowbase + nl) * 1024 + h * 64 + seg * 8);

  // GEMM1 tiling: wm1 = wave&3 (n-base wm1*16), wn1 = wave>>2 (r-base
  // wn1*144, 9 frags).  GEMM2: frag-rows wave + 8j (j < nJ), 5 d-frags.
  const int wm1 = wave & 3;
  const int wn1 = wave >> 2;
  const int nJ  = (wave < 2) ? 3 : 2;

  f32x4 acc2[3][5] = {};

#define KV_GEMM2(KPo, VTo)                                                   \
  _Pragma("unroll") for (int ks = 0; ks < 2; ++ks) {                         \
    const int cb = ks * 64 + quad * 16;                                      \
    bf16x8 bfr2[5];                                                          \
    _Pragma("unroll") for (int fd = 0; fd < 5; ++fd) {                       \
      const int d = fd * 16 + l15;                                           \
      const int s2 = ((d & 7) ^ ((d >> 3) & 7)) << 4;                        \
      bfr2[fd] = *(const bf16x8*)((VTo) + d * 128 + (cb ^ s2));              \
    }                                                                        \
    _Pragma("unroll") for (int j = 0; j < 3; ++j) {                          \
      if (j < nJ) {                                                          \
        const int r2 = (wave + 8 * j) * 16 + l15;                            \
        const bf16x8 af2 =                                                   \
            *(const bf16x8*)((KPo) + r2 * 128 + (cb ^ ((r2 & 7) << 4)));     \
        _Pragma("unroll") for (int fd = 0; fd < 5; ++fd)                     \
            acc2[j][fd] = __builtin_amdgcn_mfma_f32_16x16x32_bf16(           \
                af2, bfr2[fd], acc2[j][fd], 0, 0, 0);                        \
      }                                                                      \
    }                                                                        \
  }

  for (int t = 0; t < 16; ++t) {
    const int q = t & 1;
    char* Kt  = KtB + q * 8192;
    char* KP  = KPB + q * 36864;
    char* VT  = VTB + q * 10240;
    char* KPo = KPB + (q ^ 1) * 36864;
    char* VTo = VTB + (q ^ 1) * 10240;

    asm volatile("s_waitcnt vmcnt(0)" ::: "memory");  // K(t) LDS, V(t) regs
    __builtin_amdgcn_s_barrier();  // + KP/VT[q] free (readers done @ t-1)
    asm volatile("" ::: "memory");

    // VT[q] rows 0..63 = V(t)^T (swizzled b16 scatter)
#pragma unroll
    for (int j = 0; j < 8; ++j) {
      const int d = seg * 8 + j;
      const int s = ((d & 7) ^ ((d >> 3) & 7)) << 4;
      *(unsigned short*)(VT + d * 128 + ((nl * 2) ^ s)) = vc[j];
    }
    // prefetch tile t+1 (Kt[q^1] free: its readers ended at barrier t-1)
    if (t < 15) {
      const long nb1 = rowbase + (long)(t + 1) * 64;
      gld16(Kb + (nb1 + rK) * 1024 + h * 64 + gK * 8,
            KtB + (q ^ 1) * 8192 + tid * 16);
      vc = *(const u16x8*)(Vb + (nb1 + nl) * 1024 + h * 64 + seg * 8);
    }
    // GEMM1: kp = K_tile(64n x 64d) . projb^T -> C[n][r]
    f32x4 acc1[9] = {};
#pragma unroll
    for (int ks = 0; ks < 2; ++ks) {
      const int cb = ks * 64 + quad * 16;
      const bf16x8 af1 =
          *(const bf16x8*)(Kt + (wm1 * 16 + l15) * 128 + (cb ^ swL));
      bf16x8 bfr[9];
#pragma unroll
      for (int fn = 0; fn < 9; ++fn)
        bfr[fn] = *(const bf16x8*)(Pj + (wn1 * 144 + fn * 16 + l15) * 128 +
                                   (cb ^ swL));
#pragma unroll
      for (int fn = 0; fn < 9; ++fn)
        acc1[fn] = __builtin_amdgcn_mfma_f32_16x16x32_bf16(af1, bfr[fn],
                                                           acc1[fn], 0, 0, 0);
    }
    // epi: relu+eps (r<266 else 0), pack 4 n-consecutive -> KP[q][r][n]
    {
      const int nb = (wm1 * 16 + quad * 4) * 2;  // byte base in 128B row
#pragma unroll
      for (int fn = 0; fn < 9; ++fn) {
        const int r = wn1 * 144 + fn * 16 + l15;
        const bool ok = (r < 266);
        union { __hip_bfloat16 hh[4]; uint2 u; } pk;
#pragma unroll
        for (int ii = 0; ii < 4; ++ii) {
          float v = acc1[fn][ii];
          v = ok ? (fmaxf(v, 0.f) + EPS_F) : 0.f;
          pk.hh[ii] = (__hip_bfloat16)v;
        }
        *(uint2*)(KP + r * 128 + (nb ^ ((r & 7) << 4))) = pk.u;
      }
    }
    // GEMM2 on previous tile (buffers q^1); skip at t==0
    if (t > 0) { KV_GEMM2(KPo, VTo) }
    asm volatile("s_waitcnt lgkmcnt(0)" ::: "memory");  // my KP/VT writes done
    __builtin_amdgcn_s_barrier();
    asm volatile("" ::: "memory");
  }
  // epilogue: GEMM2 for tile 15 (buffers q=1; visible after last barrier)
  { KV_GEMM2(KPB + 36864, VTB + 10240) }
#undef KV_GEMM2

  // store partial kvp[blockIdx][288][80] f32 (layout unchanged)
  float* dst = kvp + (long)blockIdx.x * 23040;
#pragma unroll
  for (int j = 0; j < 3; ++j) {
    if (j < nJ) {
      const int rb = (wave + 8 * j) * 16 + quad * 4;
#pragma unroll
      for (int fd = 0; fd < 5; ++fd) {
        const int d = fd * 16 + l15;
#pragma unroll
        for (int ii = 0; ii < 4; ++ii)
          dst[(long)(rb + ii) * 80 + d] = acc2[j][fd][ii];
      }
    }
  }
}

// kvxb[bh][d][r] bf16 = sum_slab kvp[slab][bh][r][d]
// R14: 256 blocks = 64 bh x 4 d-quarters (20 d each); padded-LDS transpose.
__global__ void __launch_bounds__(256)
finalize_kvx2(const float* __restrict__ kvp,
              __hip_bfloat16* __restrict__ kvxb) {
  __shared__ float lf[288 * 21];
  const int bh = blockIdx.x >> 2, dq = blockIdx.x & 3, t = threadIdx.x;
  for (int p = 0; p < 23; ++p) {
    const int q = p * 256 + t;
    if (q < 5760) {
      const int r = q / 20, dl = q - r * 20;
      float s = 0.f;
#pragma unroll
      for (int sl = 0; sl < 4; ++sl)
        s += kvp[(long)(sl * 64 + bh) * 23040 + r * 80 + dq * 20 + dl];
      lf[r * 21 + dl] = s;
    }
  }
  __syncthreads();
  for (int p = 0; p < 23; ++p) {
    const int o = p * 256 + t;
    if (o < 5760) {
      const int dl = o / 288, r = o - dl * 288;
      kvxb[(long)bh * 23040 + (long)(dq * 20 + dl) * 288 + r] =
          (__hip_bfloat16)lf[r * 21 + dl];
    }
  }
}

// ---------------------------------------------------------------------------
// favor_out: qp = relu(Q.projb^T)+eps ; out = (qp . kvxb^T)/denom, merged
// (unchanged from R10-verified)
// ---------------------------------------------------------------------------
__global__ void __launch_bounds__(512, 2)
favor_out(const __hip_bfloat16* __restrict__ Qb,
          const __hip_bfloat16* __restrict__ kvxb_g,
          const __hip_bfloat16* __restrict__ projb_g,
          __hip_bfloat16* __restrict__ outm) {
  __shared__ __align__(16) char sm[160512];
  char* Pj = sm;
  char* KX = sm + 36864;
  char* QP = sm + 84224;
  float* Dsh = (float*)(sm + 160000);

  const int tid  = threadIdx.x;
  const int lane = tid & 63;
  const int wave = tid >> 6;
  const int quad = lane >> 4;
  const int l15  = lane & 15;
  const int swL  = (l15 & 7) << 4;

  const int bh  = blockIdx.x >> 3;
  const int rb8 = blockIdx.x & 7;
  const int b = bh >> 4, h = bh & 15;
  const long rowbase = (long)b * 4096 + (long)rb8 * 512;

  for (int p = 0; p < 5; ++p) {
    const int idx = p * 512 + tid;
    if (idx < 2304) {
      const int r = idx >> 3, g = (idx & 7) ^ (r & 7);
      gld16(projb_g + r * 64 + g * 8, Pj + idx * 16);
    }
  }
  {
    const __hip_bfloat16* src = kvxb_g + (long)bh * 23040;
#pragma unroll
    for (int p = 0; p < 6; ++p) {
      const int idx = p * 512 + tid;
      if (idx < 2880) {
        const int d = idx / 36, g = idx % 36;
        const bf16x8 v = *(const bf16x8*)(src + d * 288 + g * 8);
        *(bf16x8*)(KX + d * 592 + g * 16) = v;
      }
    }
  }
  const int rS = tid >> 3, gS = (tid & 7) ^ (rS & 7);
  const int rS2 = rS + 64, gS2 = (tid & 7) ^ (rS2 & 7);
  u16x8 qv0 = *(const u16x8*)(Qb + (rowbase + rS) * 1024 + h * 64 + gS * 8);
  u16x8 qv1 = *(const u16x8*)(Qb + (rowbase + rS2) * 1024 + h * 64 + gS2 * 8);

  const int wm1 = wave >> 2;
  const int wn1 = wave & 3;

  for (int s = 0; s < 4; ++s) {
    *(u16x8*)(QP + tid * 16) = qv0;
    *(u16x8*)(QP + 8192 + tid * 16) = qv1;
    asm volatile("s_waitcnt lgkmcnt(0)" ::: "memory");
    if (s == 0) asm volatile("s_waitcnt vmcnt(0)" ::: "memory");
    __builtin_amdgcn_s_barrier();
    asm volatile("" ::: "memory");
    f32x4 acc1[9][2] = {};
#pragma unroll
    for (int ks = 0; ks < 2; ++ks) {
      const int cb = ks * 64 + quad * 16;
      bf16x8 bfr[2];
#pragma unroll
      for (int fn = 0; fn < 2; ++fn)
        bfr[fn] = *(const bf16x8*)(QP + (wn1 * 32 + fn * 16 + l15) * 128 +
                                   (cb ^ swL));
      bf16x8 af[9];
#pragma unroll
      for (int fm = 0; fm < 9; ++fm)
        af[fm] = *(const bf16x8*)(Pj + (wm1 * 144 + fm * 16 + l15) * 128 +
                                  (cb ^ swL));
#pragma unroll
      for (int fm = 0; fm < 9; ++fm)
#pragma unroll
        for (int fn = 0; fn < 2; ++fn)
          acc1[fm][fn] = __builtin_amdgcn_mfma_f32_16x16x32_bf16(
              af[fm], bfr[fn], acc1[fm][fn], 0, 0, 0);
    }
    if (s < 3) {
      const long n1 = (long)(s + 1) * 128;
      qv0 = *(const u16x8*)(Qb + (rowbase + n1 + rS) * 1024 + h * 64 + gS * 8);
      qv1 = *(const u16x8*)(Qb + (rowbase + n1 + rS2) * 1024 + h * 64 +
                            gS2 * 8);
    }
    __builtin_amdgcn_s_barrier();
    asm volatile("" ::: "memory");
#pragma unroll
    for (int fm = 0; fm < 9; ++fm) {
      const int r0 = wm1 * 144 + fm * 16 + quad * 4;
#pragma unroll
      for (int fn = 0; fn < 2; ++fn) {
        const int n = wn1 * 32 + fn * 16 + l15;
        union { __hip_bfloat16 hh[4]; uint2 u; } pk;
#pragma unroll
        for (int ii = 0; ii < 4; ++ii) {
          float v = acc1[fm][fn][ii];
          v = (r0 + ii < 266) ? (fmaxf(v, 0.f) + EPS_F) : 0.f;
          pk.hh[ii] = (__hip_bfloat16)v;
        }
        *(uint2*)(QP + n * 592 + r0 * 2) = pk.u;
      }
    }
    asm volatile("s_waitcnt lgkmcnt(0)" ::: "memory");
    __builtin_amdgcn_s_barrier();
    asm volatile("" ::: "memory");
    f32x4 acc2[5] = {};
#pragma unroll
    for (int ks = 0; ks < 9; ++ks) {
      const int cb = ks * 64 + quad * 16;
      const bf16x8 af = *(const bf16x8*)(QP + (wave * 16 + l15) * 592 + cb);
      bf16x8 bfr[5];
#pragma unroll
      for (int fd = 0; fd < 5; ++fd)
        bfr[fd] = *(const bf16x8*)(KX + (fd * 16 + l15) * 592 + cb);
#pragma unroll
      for (int fd = 0; fd < 5; ++fd)
        acc2[fd] = __builtin_amdgcn_mfma_f32_16x16x32_bf16(af, bfr[fd],
                                                           acc2[fd], 0, 0, 0);
    }
    if (l15 == 0) {
#pragma unroll
      for (int ii = 0; ii < 4; ++ii)
        Dsh[wave * 16 + quad * 4 + ii] = acc2[4][ii];
    }
    asm volatile("s_waitcnt lgkmcnt(0)" ::: "memory");
    __builtin_amdgcn_s_barrier();
    asm volatile("" ::: "memory");
#pragma unroll
    for (int ii = 0; ii < 4; ++ii) {
      const int nloc = wave * 16 + quad * 4 + ii;
      const float den = Dsh[nloc];
      const float dinv = (den > 1e-30f) ? (1.f / den) : 0.f;
      __hip_bfloat16* rowp =
          outm + (rowbase + (long)s * 128 + nloc) * 1024 + h * 64;
#pragma unroll
      for (int fd = 0; fd < 4; ++fd)
        rowp[fd * 16 + l15] = (__hip_bfloat16)(acc2[fd][ii] * dinv);
    }
  }
}

// xb = bf16(x), 8 elements/thread
__global__ void cvt_x(const float* __restrict__ x,
                      __hip_bfloat16* __restrict__ xb) {
  const long i = ((long)blockIdx.x * 256 + threadIdx.x) * 8;
  const float4 f0 = *(const float4*)(x + i);
  const float4 f1 = *(const float4*)(x + i + 4);
  union { __hip_bfloat16 h[8]; uint4 u; } r;
  r.h[0] = (__hip_bfloat16)f0.x; r.h[1] = (__hip_bfloat16)f0.y;
  r.h[2] = (__hip_bfloat16)f0.z; r.h[3] = (__hip_bfloat16)f0.w;
  r.h[4] = (__hip_bfloat16)f1.x; r.h[5] = (__hip_bfloat16)f1.y;
  r.h[6] = (__hip_bfloat16)f1.z; r.h[7] = (__hip_bfloat16)f1.w;
  *(uint4*)(xb + i) = r.u;
}

// weight transposes (z=0..3) + projb prep (z=4) in one launch.
__global__ void prep_w(const float* __restrict__ s0,
                       const float* __restrict__ s1,
                       const float* __restrict__ s2,
                       const float* __restrict__ s3,
                       const float* __restrict__ proj,
                       __hip_bfloat16* __restrict__ dq,
                       __hip_bfloat16* __restrict__ dwo,
                       __hip_bfloat16* __restrict__ projb) {
  const int z = blockIdx.z;
  if (z == 4) {
    const int i = (blockIdx.y * 32 + blockIdx.x) * 256 + (int)threadIdx.x;
    if (i < 288 * 64) {
      const int r = i >> 6;
      __hip_bfloat16 v = (__hip_bfloat16)0.f;
      if (r < 266) v = (__hip_bfloat16)proj[i];
      projb[i] = v;
    }
    return;
  }
  __shared__ float t[32][33];
  const float* src = (z == 0) ? s0 : (z == 1) ? s1 : (z == 2) ? s2 : s3;
  __hip_bfloat16* dst = (z < 3) ? (dq + (long)z * 1048576) : dwo;
  const int k0 = blockIdx.x * 32, n0 = blockIdx.y * 32;
  const int tx = threadIdx.x & 31, ty = threadIdx.x >> 5;
#pragma unroll
  for (int i = 0; i < 4; ++i)
    t[ty + i * 8][tx] = src[(long)(k0 + ty + i * 8) * 1024 + n0 + tx];
  __syncthreads();
#pragma unroll
  for (int i = 0; i < 4; ++i)
    dst[(long)(n0 + ty + i * 8) * 1024 + k0 + tx] =
        (__hip_bfloat16)t[tx][ty + i * 8];
}

// ---------------------------------------------------------------------------
extern "C" void kernel_launch(void* const* d_in, const int* in_sizes, int n_in,
                              void* d_out, int out_size, void* d_ws,
                              size_t ws_size, hipStream_t stream) {
  const float* x    = (const float*)d_in[0];
  const float* Wq   = (const float*)d_in[1];
  const float* Wk   = (const float*)d_in[2];
  const float* Wv   = (const float*)d_in[3];
  const float* Wo   = (const float*)d_in[4];
  const float* bo   = (const float*)d_in[5];
  const float* proj = (const float*)d_in[6];
  float* out = (float*)d_out;
  char* ws = (char*)d_ws;

  // ws layout (bytes); total 135,630,848 (proven fit)
  constexpr long o_wqkvt = 0;            // 6,291,456
  constexpr long o_wot   = 6291456;      // 2,097,152
  constexpr long o_projb = 8388608;      // 36,864
  constexpr long o_Qb    = 8425472;      // 33,554,432
  constexpr long o_Kb    = 41979904;     // 33,554,432 (alias outm)
  constexpr long o_Vb    = 75534336;     // 33,554,432
  constexpr long o_xb    = 109088768;    // 33,554,432 (alias kvp/kvxb)
  constexpr long o_kvp   = 109088768;    // 4*64*23040*4 = 23,592,960
  constexpr long o_kvxb  = 132681728;    // 64*23040*2   =  2,949,120

  __hip_bfloat16* wqkvt = (__hip_bfloat16*)(ws + o_wqkvt);
  __hip_bfloat16* wot   = (__hip_bfloat16*)(ws + o_wot);
  __hip_bfloat16* projb = (__hip_bfloat16*)(ws + o_projb);
  __hip_bfloat16* Qb    = (__hip_bfloat16*)(ws + o_Qb);
  __hip_bfloat16* Kb    = (__hip_bfloat16*)(ws + o_Kb);
  __hip_bfloat16* Vb    = (__hip_bfloat16*)(ws + o_Vb);
  __hip_bfloat16* xb    = (__hip_bfloat16*)(ws + o_xb);
  float*          kvp   = (float*)(ws + o_kvp);
  __hip_bfloat16* kvxb  = (__hip_bfloat16*)(ws + o_kvxb);
  __hip_bfloat16* outm  = Kb;  // alias: Kb dead after favor_kv

  // prep
  cvt_x<<<8192, 256, 0, stream>>>(x, xb);
  prep_w<<<dim3(32, 32, 5), 256, 0, stream>>>(Wq, Wk, Wv, Wo, proj, wqkvt,
                                              wot, projb);

  // S1 fused: [Qb|Kb|Vb] = xb . wqkvt^T  (256^2 pipelined GEMM, EPI7)
  gemm256<7><<<768, 512, 0, stream>>>(xb, 1024, wqkvt, 1024, Qb, 0, 64, 12,
                                      1024, nullptr);

  // phase A fused: kvp partials, then reduce+transpose to kvxb
  favor_kv<<<256, 512, 0, stream>>>(Kb, Vb, projb, kvp);
  finalize_kvx2<<<256, 256, 0, stream>>>(kvp, kvxb);

  // phase B fused: outm = (relu(Q.projb^T)+eps) . kvxb^T / denom, merged
  favor_out<<<512, 512, 0, stream>>>(Qb, kvxb, projb, outm);

  // S5: out(f32) = outm . wot^T + bo  (256^2 pipelined GEMM, EPI5)
  gemm256<5><<<256, 512, 0, stream>>>(outm, 1024, wot, 1024, out, 1024, 64, 4,
                                      1024, bo);
}